// Round 15
// baseline (190.570 us; speedup 1.0000x reference)
//
#include <hip/hip_runtime.h>
#include <hip/hip_bf16.h>

typedef __attribute__((ext_vector_type(8))) short bf16x8;
typedef __attribute__((ext_vector_type(4))) float f32x4;
typedef __attribute__((ext_vector_type(16))) float f32x16;
typedef unsigned short u16;

__device__ __forceinline__ u16 f2bf(float f) {
  unsigned int u = __builtin_bit_cast(unsigned int, f);
  u += 0x7fffu + ((u >> 16) & 1u);
  return (u16)(u >> 16);
}
__device__ __forceinline__ float bf2f(unsigned int h) {
  unsigned int u = h << 16;
  return __builtin_bit_cast(float, u);
}

__device__ __forceinline__ void gload_lds16(const void* g, void* l) {
  __builtin_amdgcn_global_load_lds(
      (const __attribute__((address_space(1))) void*)g,
      (__attribute__((address_space(3))) void*)l, 16, 0, 0);
}

#define BAR() __builtin_amdgcn_s_barrier()
#define VMC(N) asm volatile("s_waitcnt vmcnt(%0)" ::"n"(N) : "memory")

// ---------------------------------------------------------------------------
// r8-core 128x256 2-phase counted-vmcnt NT GEMM, 32x32x16 MFMA port.
// C[m][n] = sum_k A[m][k]*Bt[n][k]. 512 thr = 8 waves (2wr x 4wc),
// per-wave 64x64 as 2x2 tiles of 32x32. K-tile 64 = 4 k-slices of 16.
// A/B frag: lane l holds row/col = l&31, k = ks*16 + (l>>5)*8 .. +7.
// C/D frag [m74/m101]: col = lane&31, row = (reg&3) + 8*(reg>>2) + 4*(l>>5).
// Schedule (unchanged, r8-proven): ph0: rdA[8]+rdB[8]; stageB(t+2); BAR;
// mma ks0-1 [8 MFMA]. ph1: VMC(4); BAR; stageA(t+2); mma ks2-3 [8 MFMA].
// T1 XCD-bijective block swizzle (m204) kept (FETCH -44%, r14).
// LDS swizzle: 16B-block b16 ^= (row&7); staging source pre-swizzled
// (0 bank conflicts; new read pattern re-derived conflict-free).
// EPI 4: S  — P' = exp2(acc*K2 + c2[col]) bf16 + atomic rowsum
// EPI 5: PV — f32 out / rowsum          EPI 7: TV — fused T | V^T(+bias)
// ---------------------------------------------------------------------------
template <int EPI>
__global__ __launch_bounds__(512, 2) void gemm2t(
    const u16* __restrict__ Abase, const u16* __restrict__ Btbase,
    const float* __restrict__ p0, float* __restrict__ p1,
    const float* __restrict__ p2, void* __restrict__ out0,
    void* __restrict__ out1, int Kd, int ldc, long long sAz, long long sBz,
    long long sCz) {
  constexpr int ASZ = 16384;
  constexpr int BSZ = 32768;
  constexpr int BBASE = 2 * ASZ;
  __shared__ char lds[2 * ASZ + 3 * BSZ];  // 131072 B

  // T1 bijective XCD remap (m204)
  const int gx = gridDim.x, gy = gridDim.y;
  const int nwg = gx * gy * gridDim.z;
  const int orig = blockIdx.x + gx * (blockIdx.y + gy * blockIdx.z);
  const int q = nwg >> 3, r = nwg & 7;
  const int xcd = orig & 7, loc = orig >> 3;
  const int wgid =
      (xcd < r ? xcd * (q + 1) : r * (q + 1) + (xcd - r) * q) + loc;
  const int bxi = wgid % gx;
  const int byi = (wgid / gx) % gy;
  const int z = wgid / (gx * gy);

  const int tid = threadIdx.x;
  const int w = tid >> 6, l = tid & 63;
  const int wr = w >> 2, wc = w & 3;
  const int l32 = l & 31, h = l >> 5;
  const int bm = byi * 128, bn = bxi * 256;
  const u16* A = Abase + (size_t)z * sAz;
  const u16* Bt = Btbase + (size_t)z * sBz;
  const int NT = Kd >> 6;

  const int kbp = ((tid & 7) ^ ((tid >> 3) & 7)) * 8;
  const int drow = tid >> 3;
  const u16* gA[2];
  const u16* gB[4];
#pragma unroll
  for (int u = 0; u < 2; ++u)
    gA[u] = A + (size_t)(bm + u * 64 + drow) * Kd + kbp;
#pragma unroll
  for (int u = 0; u < 4; ++u)
    gB[u] = Bt + (size_t)(bn + u * 64 + drow) * Kd + kbp;

  auto stageA = [&](int kt) {
    char* d = lds + (kt & 1) * ASZ + tid * 16;
#pragma unroll
    for (int u = 0; u < 2; ++u) gload_lds16(gA[u] + kt * 64, d + u * 8192);
  };
  auto stageB = [&](int kt) {
    char* d = lds + BBASE + (kt % 3) * BSZ + tid * 16;
#pragma unroll
    for (int u = 0; u < 4; ++u) gload_lds16(gB[u] + kt * 64, d + u * 8192);
  };

  // fragment read offsets: row rA0+mf*32 (A) / rB0+nf*32 (B), 16B-block
  // (ks*2+h) ^ (row&7); row&7 == l32&7 for all mf/nf (32 ≡ 0 mod 8).
  const int rA0 = wr * 64 + l32;
  const int rB0 = wc * 64 + l32;
  const int sel = l32 & 7;
  int koff[4];
#pragma unroll
  for (int ks = 0; ks < 4; ++ks) koff[ks] = ((ks * 2 + h) ^ sel) << 4;

  f32x16 acc[2][2] = {};   // [mi][ni]
  bf16x8 a[2][4];          // [mi][ks]
  bf16x8 b[2][4];          // [ni][ks]

  auto rdA = [&](int kt) {
    const char* p = lds + (kt & 1) * ASZ;
#pragma unroll
    for (int mi = 0; mi < 2; ++mi)
#pragma unroll
      for (int ks = 0; ks < 4; ++ks)
        a[mi][ks] =
            *(const bf16x8*)(p + (rA0 + mi * 32) * 128 + koff[ks]);
  };
  auto rdB = [&](int kt) {
    const char* p = lds + BBASE + (kt % 3) * BSZ;
#pragma unroll
    for (int ni = 0; ni < 2; ++ni)
#pragma unroll
      for (int ks = 0; ks < 4; ++ks)
        b[ni][ks] =
            *(const bf16x8*)(p + (rB0 + ni * 32) * 128 + koff[ks]);
  };
  auto mma2 = [&](int ks0) {
    __builtin_amdgcn_s_setprio(1);
#pragma unroll
    for (int ks = 0; ks < 2; ++ks)
#pragma unroll
      for (int mi = 0; mi < 2; ++mi)
#pragma unroll
        for (int ni = 0; ni < 2; ++ni)
          acc[mi][ni] = __builtin_amdgcn_mfma_f32_32x32x16_bf16(
              a[mi][ks0 + ks], b[ni][ks0 + ks], acc[mi][ni], 0, 0, 0);
    __builtin_amdgcn_s_setprio(0);
  };

  stageB(0);
  stageA(0);
  stageB(1);
  stageA(1);
  VMC(6);
  BAR();

  for (int t = 0; t < NT; ++t) {
    rdA(t);
    rdB(t);
    if (t + 2 < NT) stageB(t + 2);
    BAR();
    mma2(0);
    if (t + 2 < NT) VMC(4); else VMC(0);
    BAR();
    if (t + 2 < NT) stageA(t + 2);
    mma2(2);
  }

  // epilogue. C/D: col = l&31, row = (reg&3) + 8*(reg>>2) + 4*h  [m74/m101]
  if constexpr (EPI == 4) {
    constexpr float K2 = 0.045084834f;  // log2(e)/32
    u16* C = (u16*)out0 + (size_t)z * sCz;
    const float* cc = p0 + z * 2048;    // pre-scaled c2 = c*K2
    float* rs = p1 + z * 2048;
    float psum[2][16] = {};
#pragma unroll
    for (int ni = 0; ni < 2; ++ni) {
      const int col = bn + wc * 64 + ni * 32 + l32;
      const float cj2 = cc[col];
#pragma unroll
      for (int mi = 0; mi < 2; ++mi) {
#pragma unroll
        for (int rg = 0; rg < 16; ++rg) {
          const int row =
              bm + wr * 64 + mi * 32 + (rg & 3) + 8 * (rg >> 2) + 4 * h;
          const float pv = exp2f(fmaf(acc[mi][ni][rg], K2, cj2));
          C[(size_t)row * ldc + col] = f2bf(pv);
          psum[mi][rg] += pv;
        }
      }
    }
#pragma unroll
    for (int off = 1; off <= 16; off <<= 1)
#pragma unroll
      for (int mi = 0; mi < 2; ++mi)
#pragma unroll
        for (int rg = 0; rg < 16; ++rg)
          psum[mi][rg] += __shfl_xor(psum[mi][rg], off, 64);
    if (l32 == 0) {
#pragma unroll
      for (int mi = 0; mi < 2; ++mi)
#pragma unroll
        for (int rg = 0; rg < 16; ++rg) {
          const int row =
              bm + wr * 64 + mi * 32 + (rg & 3) + 8 * (rg >> 2) + 4 * h;
          atomicAdd(&rs[row], psum[mi][rg]);
        }
    }
  } else if constexpr (EPI == 5) {
    float* C = (float*)out0 + (size_t)z * sCz;
    const float* rs = p1 + z * 2048;
#pragma unroll
    for (int ni = 0; ni < 2; ++ni) {
      const int col = bn + wc * 64 + ni * 32 + l32;
#pragma unroll
      for (int mi = 0; mi < 2; ++mi)
#pragma unroll
        for (int rg = 0; rg < 16; ++rg) {
          const int row =
              bm + wr * 64 + mi * 32 + (rg & 3) + 8 * (rg >> 2) + 4 * h;
          C[(size_t)row * ldc + col] = acc[mi][ni][rg] / rs[row];
        }
    }
  } else {  // EPI 7: TV fused
    const int mat = bn >> 10;
    u16* T = (u16*)out0;
    u16* V = (u16*)out1;
#pragma unroll
    for (int ni = 0; ni < 2; ++ni) {
      const int oc = (bn + wc * 64 + ni * 32 + l32) & 1023;
      if (mat == 0) {
#pragma unroll
        for (int mi = 0; mi < 2; ++mi)
#pragma unroll
          for (int rg = 0; rg < 16; ++rg) {
            const int row =
                bm + wr * 64 + mi * 32 + (rg & 3) + 8 * (rg >> 2) + 4 * h;
            T[(size_t)row * 1024 + oc] = f2bf(acc[mi][ni][rg]);
          }
      } else {
        const float bb2 = p2[oc];
#pragma unroll
        for (int mi = 0; mi < 2; ++mi)
#pragma unroll
          for (int ra = 0; ra < 4; ++ra) {  // reg quad -> 4 consecutive s
            const int sbase = bm + wr * 64 + mi * 32 + 8 * ra + 4 * h;
            const int bz = sbase >> 11, sdx = sbase & 2047;
            ushort4 pk;
            pk.x = f2bf(acc[mi][ni][4 * ra + 0] + bb2);
            pk.y = f2bf(acc[mi][ni][4 * ra + 1] + bb2);
            pk.z = f2bf(acc[mi][ni][4 * ra + 2] + bb2);
            pk.w = f2bf(acc[mi][ni][4 * ra + 3] + bb2);
            *(ushort4*)&V[((size_t)bz * 1024 + oc) * 2048 + sdx] = pk;
          }
      }
    }
  }
}

// ---------------------------------------------------------------------------
// 128x128 2-phase core (16x16x32), split-K M partials (f32 slices).
// ---------------------------------------------------------------------------
__global__ __launch_bounds__(256) void gemmM(
    const u16* __restrict__ Abase, const u16* __restrict__ Btbase,
    float* __restrict__ out0, int Kd, int Kext, int ldc, long long sAz,
    long long sBz, long long sCz) {
  constexpr int ASZ = 16384;
  constexpr int BSZ = 16384;
  constexpr int BBASE = 2 * ASZ;
  __shared__ char lds[2 * ASZ + 3 * BSZ];

  const int tid = threadIdx.x;
  const int w = tid >> 6, l = tid & 63;
  const int wr = w >> 1, wc = w & 1;
  const int lq = l >> 4, lr = l & 15;
  const int bm = blockIdx.y * 128, bn = blockIdx.x * 128;
  const int z = blockIdx.z;
  const u16* A = Abase + (size_t)z * sAz;
  const u16* Bt = Btbase + (size_t)z * sBz;
  const int NT = Kext >> 6;

  const int kbp = ((tid & 7) ^ ((tid >> 3) & 7)) * 8;
  const int drow = tid >> 3;
  const u16* gA[4];
  const u16* gB[4];
#pragma unroll
  for (int u = 0; u < 4; ++u) {
    gA[u] = A + (size_t)(bm + u * 32 + drow) * Kd + kbp;
    gB[u] = Bt + (size_t)(bn + u * 32 + drow) * Kd + kbp;
  }

  auto stageA = [&](int kt) {
    char* d = lds + (kt & 1) * ASZ + tid * 16;
#pragma unroll
    for (int u = 0; u < 4; ++u) gload_lds16(gA[u] + kt * 64, d + u * 4096);
  };
  auto stageB = [&](int kt) {
    char* d = lds + BBASE + (kt % 3) * BSZ + tid * 16;
#pragma unroll
    for (int u = 0; u < 4; ++u) gload_lds16(gB[u] + kt * 64, d + u * 4096);
  };

  const int rA = wr * 64 + lr;
  const int rB0 = wc * 64 + lr;
  int aoff[2];
#pragma unroll
  for (int kh = 0; kh < 2; ++kh)
    aoff[kh] = rA * 128 + (((kh * 4 + lq) ^ (rA & 7)) << 4);

  f32x4 acc[4][2][2] = {};
  bf16x8 a[2][4];
  bf16x8 bb[2][2][2];

  auto rdA = [&](int kt) {
    const char* p = lds + (kt & 1) * ASZ;
#pragma unroll
    for (int kh = 0; kh < 2; ++kh)
#pragma unroll
      for (int mf = 0; mf < 4; ++mf)
        a[kh][mf] = *(const bf16x8*)(p + aoff[kh] + mf * 2048);
  };
  auto rdB = [&](int kt) {
    const char* p = lds + BBASE + (kt % 3) * BSZ;
#pragma unroll
    for (int nh = 0; nh < 2; ++nh) {
      const int rB = rB0 + nh * 32;
#pragma unroll
      for (int kh = 0; kh < 2; ++kh) {
        const int o = rB * 128 + (((kh * 4 + lq) ^ (rB & 7)) << 4);
#pragma unroll
        for (int nf = 0; nf < 2; ++nf)
          bb[nh][kh][nf] = *(const bf16x8*)(p + o + nf * 2048);
      }
    }
  };
  auto mma = [&](int kh) {
#pragma unroll
    for (int nh = 0; nh < 2; ++nh)
#pragma unroll
      for (int mf = 0; mf < 4; ++mf)
#pragma unroll
        for (int nf = 0; nf < 2; ++nf)
          acc[mf][nh][nf] = __builtin_amdgcn_mfma_f32_16x16x32_bf16(
              a[kh][mf], bb[nh][kh][nf], acc[mf][nh][nf], 0, 0, 0);
  };

  stageB(0);
  stageA(0);
  stageB(1);
  stageA(1);
  VMC(8);
  BAR();

  for (int t = 0; t < NT; ++t) {
    rdA(t);
    rdB(t);
    if (t + 2 < NT) stageB(t + 2);
    BAR();
    mma(0);
    if (t + 2 < NT) VMC(4); else VMC(0);
    BAR();
    if (t + 2 < NT) stageA(t + 2);
    mma(1);
  }

  float* C = out0 + (size_t)z * sCz;
#pragma unroll
  for (int nh = 0; nh < 2; ++nh)
#pragma unroll
    for (int nf = 0; nf < 2; ++nf) {
      const int col = bn + wc * 64 + nh * 32 + nf * 16 + lr;
#pragma unroll
      for (int mf = 0; mf < 4; ++mf) {
        const int row = bm + wr * 64 + mf * 16 + lq * 4;
#pragma unroll
        for (int e = 0; e < 4; ++e)
          C[(size_t)(row + e) * ldc + col] = acc[mf][nh][nf][e];
      }
    }
}

// ---------------------------------------------------------------------------
// prep: one dispatch, 256-thr blocks, flat bid ranges.
// ---------------------------------------------------------------------------
__global__ __launch_bounds__(256) void prep(
    const float* __restrict__ x, const float* __restrict__ Wq,
    const float* __restrict__ Wk, const float* __restrict__ Wv,
    const float* __restrict__ bq, u16* __restrict__ xb,
    u16* __restrict__ Wqb, u16* __restrict__ Wkb, u16* __restrict__ WtTV,
    float* __restrict__ vvec) {
  const int bid = blockIdx.x;
  const int tid = threadIdx.x;
  if (bid < 8192) {
    const int i = bid * 256 + tid;
    const float4 v = ((const float4*)x)[i];
    ushort4 o;
    o.x = f2bf(v.x);
    o.y = f2bf(v.y);
    o.z = f2bf(v.z);
    o.w = f2bf(v.w);
    ((ushort4*)xb)[i] = o;
  } else if (bid < 11264) {
    const int b = bid - 8192;
    const int zz = b >> 10, t2 = b & 1023;
    const int k0 = (t2 >> 5) * 32, n0 = (t2 & 31) * 32;
    const int tx = tid & 31, ty0 = tid >> 5;
    if (zz == 2) {
      __shared__ float s[32][33];
#pragma unroll
      for (int r = 0; r < 4; ++r) {
        const int row = ty0 + 8 * r;
        s[row][tx] = Wv[(size_t)(k0 + row) * 1024 + n0 + tx];
      }
      __syncthreads();
#pragma unroll
      for (int r = 0; r < 4; ++r) {
        const int row = ty0 + 8 * r;
        WtTV[1048576 + (size_t)(n0 + row) * 1024 + k0 + tx] =
            f2bf(s[tx][row]);
      }
    } else {
      const float* W = zz ? Wk : Wq;
      u16* O = zz ? Wkb : Wqb;
#pragma unroll
      for (int r = 0; r < 4; ++r) {
        const size_t i = (size_t)(k0 + ty0 + 8 * r) * 1024 + n0 + tx;
        O[i] = f2bf(W[i]);
      }
    }
  } else {
    const int d = bid - 11264;
    const float4 wv = ((const float4*)(Wk + (size_t)d * 1024))[tid];
    const float4 bv = ((const float4*)bq)[tid];
    float p = wv.x * bv.x + wv.y * bv.y + wv.z * bv.z + wv.w * bv.w;
#pragma unroll
    for (int o = 32; o; o >>= 1) p += __shfl_xor(p, o, 64);
    __shared__ float red[4];
    if ((tid & 63) == 0) red[tid >> 6] = p;
    __syncthreads();
    if (tid == 0) vvec[d] = red[0] + red[1] + red[2] + red[3];
  }
}

// ---------------------------------------------------------------------------
// mck: merged mcast | cker (range-split).
// ---------------------------------------------------------------------------
__global__ __launch_bounds__(256) void mck(const float* __restrict__ Mf,
                                           u16* __restrict__ Mt,
                                           const u16* __restrict__ xb,
                                           const float* __restrict__ v,
                                           float* __restrict__ c,
                                           float* __restrict__ rowsum) {
  const int bid = blockIdx.x;
  const int tid = threadIdx.x;
  if (bid < 1024) {
    const int i = bid * 256 + tid;
    const float4 a = ((const float4*)Mf)[i];
    const float4 b = ((const float4*)(Mf + 1048576))[i];
    const float4 cc = ((const float4*)(Mf + 2097152))[i];
    const float4 d = ((const float4*)(Mf + 3145728))[i];
    ushort4 o;
    o.x = f2bf(a.x + b.x + cc.x + d.x);
    o.y = f2bf(a.y + b.y + cc.y + d.y);
    o.z = f2bf(a.z + b.z + cc.z + d.z);
    o.w = f2bf(a.w + b.w + cc.w + d.w);
    ((ushort4*)Mt)[i] = o;
  } else {
    const int b2 = bid - 1024;
    if (b2 < 32) rowsum[b2 * 256 + tid] = 0.f;
    const int j = b2 * 8 + (tid >> 5);
    const int lane = tid & 31;
    const u16* xr = xb + (size_t)j * 1024;
    float p = 0.f;
#pragma unroll
    for (int k = 0; k < 4; ++k) {
      const int g = k * 32 + lane;
      const uint4 u = ((const uint4*)xr)[g];
      const float4 v0 = ((const float4*)v)[g * 2];
      const float4 v1 = ((const float4*)v)[g * 2 + 1];
      p += bf2f(u.x & 0xffffu) * v0.x + bf2f(u.x >> 16) * v0.y +
           bf2f(u.y & 0xffffu) * v0.z + bf2f(u.y >> 16) * v0.w +
           bf2f(u.z & 0xffffu) * v1.x + bf2f(u.z >> 16) * v1.y +
           bf2f(u.w & 0xffffu) * v1.z + bf2f(u.w >> 16) * v1.w;
    }
#pragma unroll
    for (int o = 16; o; o >>= 1) p += __shfl_xor(p, o, 64);
    if (lane == 0) c[j] = p * 0.045084834f;  // pre-scale by log2(e)/32
  }
}

// ---------------------------------------------------------------------------
extern "C" void kernel_launch(void* const* d_in, const int* in_sizes, int n_in,
                              void* d_out, int out_size, void* d_ws,
                              size_t ws_size, hipStream_t stream) {
  const float* x = (const float*)d_in[0];
  const float* Wq = (const float*)d_in[1];
  const float* bq = (const float*)d_in[2];
  const float* Wk = (const float*)d_in[3];
  const float* Wv = (const float*)d_in[5];
  const float* bv = (const float*)d_in[6];
  float* out = (float*)d_out;
  char* ws = (char*)d_ws;

  u16* xb = (u16*)ws;                          // 16 MiB [8192][1024] bf16
  u16* WtTV = (u16*)(ws + 16777216);           // 4 MiB  [Mt;Wvt][1024] bf16
  u16* Wqb = (u16*)(ws + 20971520);            // 2 MiB
  u16* Wkb = (u16*)(ws + 23068672);            // 2 MiB
  float* vvec = (float*)(ws + 25165824);       // 4 KiB
  float* cvec = (float*)(ws + 25169920);       // 32 KiB [8192]
  float* rowsum = (float*)(ws + 25202688);     // 32 KiB [8192]
  float* Mf32 = (float*)(ws + 25235456);       // 16 MiB (4 slices); T aliases
  u16* T = (u16*)(ws + 25235456);              // 16 MiB [8192][1024] bf16
  u16* Vt = (u16*)(ws + 42012672);             // 16 MiB [4][1024][2048] bf16
  u16* SP = (u16*)(ws + 58789888);             // 32 MiB [4][2048][2048] bf16

  // 1) prep: x-cast | W casts/transpose | vvec = Wk.bq
  prep<<<12288, 256, 0, stream>>>(x, Wq, Wk, Wv, bq, xb, Wqb, Wkb, WtTV,
                                  vvec);

  // 2) Mt = (Wq Wk^T)^T  split-K (4 x 256) f32 slices
  gemmM<<<dim3(8, 8, 4), 256, 0, stream>>>(Wkb, Wqb, Mf32, 1024, 256, 1024,
                                           256LL, 256LL, 1048576LL);

  // 3) merged: Mt sum-cast | cvec (+rowsum zero)
  mck<<<2048, 256, 0, stream>>>(Mf32, WtTV, xb, vvec, cvec, rowsum);

  // 4) fused T = x.Mt^T (bn<1024) | V-proj transposed (bn>=1024); grid 512
  gemm2t<7><<<dim3(8, 64, 1), 512, 0, stream>>>(
      xb, WtTV, nullptr, nullptr, bv, T, Vt, 1024, 0, 0, 0, 0);

  // 5) P' = exp2(T.x^T*K2 + c2) bf16 + atomic rowsum; grid 512
  gemm2t<4><<<dim3(8, 16, 4), 512, 0, stream>>>(
      T, xb, cvec, rowsum, nullptr, SP, nullptr, 1024, 2048, 2097152LL,
      2097152LL, 4194304LL);

  // 6) out = (P'.V) / rowsum; grid 256
  gemm2t<5><<<dim3(4, 16, 4), 512, 0, stream>>>(
      SP, Vt, nullptr, rowsum, nullptr, out, nullptr, 2048, 1024, 4194304LL,
      2097152LL, 2097152LL);
}

// Round 16
// 164.631 us; speedup vs baseline: 1.1576x; 1.1576x over previous
//
#include <hip/hip_runtime.h>
#include <hip/hip_bf16.h>

typedef __attribute__((ext_vector_type(8))) short bf16x8;
typedef __attribute__((ext_vector_type(4))) float f32x4;
typedef unsigned short u16;

__device__ __forceinline__ u16 f2bf(float f) {
  unsigned int u = __builtin_bit_cast(unsigned int, f);
  u += 0x7fffu + ((u >> 16) & 1u);
  return (u16)(u >> 16);
}
__device__ __forceinline__ float bf2f(unsigned int h) {
  unsigned int u = h << 16;
  return __builtin_bit_cast(float, u);
}

__device__ __forceinline__ void gload_lds16(const void* g, void* l) {
  __builtin_amdgcn_global_load_lds(
      (const __attribute__((address_space(1))) void*)g,
      (__attribute__((address_space(3))) void*)l, 16, 0, 0);
}

#define BAR() __builtin_amdgcn_s_barrier()
#define VMC(N) asm volatile("s_waitcnt vmcnt(%0)" ::"n"(N) : "memory")

// ---------------------------------------------------------------------------
// r8-core 128x256 2-phase counted-vmcnt NT GEMM + T1 XCD-bijective block
// swizzle (m204). C[m][n] = sum_k A[m][k]*Bt[n][k]. 512 thr = 8 waves
// (2wr x 4wc), per-wave 64x64, 16x16x32 MFMA. K-tile 64.
// LDS 128KB: A dbuf (2x16K) + B 3-ring (3x32K).
//  ph0: rdA[8]+rdB[16]; stageB(t+2)[4]; BAR; mma(kh0)[16 MFMA]
//  ph1: VMC(4) [leaves B(t+2)]; BAR; stageA(t+2)[2]; mma(kh1)[16]
// Swizzle: LDS[row][b16] = global[row][b16^(row&7)]; reads same XOR
// (0 bank conflicts, r1-r14; the r15 32x32 pattern conflicted — reverted).
// EPI 4: S  — P' = exp2(acc*K2 + c2[col]) bf16 + atomic rowsum
// EPI 5: PV — f32 out / rowsum          EPI 7: TV — fused T | V^T(+bias)
// ---------------------------------------------------------------------------
template <int EPI>
__global__ __launch_bounds__(512, 2) void gemm2t(
    const u16* __restrict__ Abase, const u16* __restrict__ Btbase,
    const float* __restrict__ p0, float* __restrict__ p1,
    const float* __restrict__ p2, void* __restrict__ out0,
    void* __restrict__ out1, int Kd, int ldc, long long sAz, long long sBz,
    long long sCz) {
  constexpr int ASZ = 16384;
  constexpr int BSZ = 32768;
  constexpr int BBASE = 2 * ASZ;
  __shared__ char lds[2 * ASZ + 3 * BSZ];  // 131072 B

  // T1: bijective XCD remap of flat block id (m204).
  const int gx = gridDim.x, gy = gridDim.y;
  const int nwg = gx * gy * gridDim.z;
  const int orig = blockIdx.x + gx * (blockIdx.y + gy * blockIdx.z);
  const int q = nwg >> 3, r = nwg & 7;
  const int xcd = orig & 7, loc = orig >> 3;
  const int wgid =
      (xcd < r ? xcd * (q + 1) : r * (q + 1) + (xcd - r) * q) + loc;
  const int bxi = wgid % gx;
  const int byi = (wgid / gx) % gy;
  const int z = wgid / (gx * gy);

  const int tid = threadIdx.x;
  const int w = tid >> 6, l = tid & 63;
  const int wr = w >> 2, wc = w & 3;
  const int lq = l >> 4, lr = l & 15;
  const int bm = byi * 128, bn = bxi * 256;
  const u16* A = Abase + (size_t)z * sAz;
  const u16* Bt = Btbase + (size_t)z * sBz;
  const int NT = Kd >> 6;

  const int kbp = ((tid & 7) ^ ((tid >> 3) & 7)) * 8;
  const int drow = tid >> 3;
  const u16* gA[2];
  const u16* gB[4];
#pragma unroll
  for (int u = 0; u < 2; ++u)
    gA[u] = A + (size_t)(bm + u * 64 + drow) * Kd + kbp;
#pragma unroll
  for (int u = 0; u < 4; ++u)
    gB[u] = Bt + (size_t)(bn + u * 64 + drow) * Kd + kbp;

  auto stageA = [&](int kt) {
    char* d = lds + (kt & 1) * ASZ + tid * 16;
#pragma unroll
    for (int u = 0; u < 2; ++u) gload_lds16(gA[u] + kt * 64, d + u * 8192);
  };
  auto stageB = [&](int kt) {
    char* d = lds + BBASE + (kt % 3) * BSZ + tid * 16;
#pragma unroll
    for (int u = 0; u < 4; ++u) gload_lds16(gB[u] + kt * 64, d + u * 8192);
  };

  const int rA = wr * 64 + lr;
  const int rB0 = wc * 64 + lr;
  int aoff[2];
#pragma unroll
  for (int kh = 0; kh < 2; ++kh)
    aoff[kh] = rA * 128 + (((kh * 4 + lq) ^ (rA & 7)) << 4);

  f32x4 acc[4][2][2] = {};   // [mf][nh][nf]
  bf16x8 a[2][4];            // [kh][mf]
  bf16x8 bb[2][2][2];        // [nh][kh][nf]

  auto rdA = [&](int kt) {
    const char* p = lds + (kt & 1) * ASZ;
#pragma unroll
    for (int kh = 0; kh < 2; ++kh)
#pragma unroll
      for (int mf = 0; mf < 4; ++mf)
        a[kh][mf] = *(const bf16x8*)(p + aoff[kh] + mf * 2048);
  };
  auto rdB = [&](int kt) {
    const char* p = lds + BBASE + (kt % 3) * BSZ;
#pragma unroll
    for (int nh = 0; nh < 2; ++nh) {
      const int rB = rB0 + nh * 32;
#pragma unroll
      for (int kh = 0; kh < 2; ++kh) {
        const int o = rB * 128 + (((kh * 4 + lq) ^ (rB & 7)) << 4);
#pragma unroll
        for (int nf = 0; nf < 2; ++nf)
          bb[nh][kh][nf] = *(const bf16x8*)(p + o + nf * 2048);
      }
    }
  };
  auto mma = [&](int kh) {
    __builtin_amdgcn_s_setprio(1);
#pragma unroll
    for (int nh = 0; nh < 2; ++nh)
#pragma unroll
      for (int mf = 0; mf < 4; ++mf)
#pragma unroll
        for (int nf = 0; nf < 2; ++nf)
          acc[mf][nh][nf] = __builtin_amdgcn_mfma_f32_16x16x32_bf16(
              a[kh][mf], bb[nh][kh][nf], acc[mf][nh][nf], 0, 0, 0);
    __builtin_amdgcn_s_setprio(0);
  };

  stageB(0);
  stageA(0);
  stageB(1);
  stageA(1);
  VMC(6);
  BAR();

  for (int t = 0; t < NT; ++t) {
    rdA(t);
    rdB(t);
    if (t + 2 < NT) stageB(t + 2);
    BAR();
    mma(0);
    if (t + 2 < NT) VMC(4); else VMC(0);
    BAR();
    if (t + 2 < NT) stageA(t + 2);
    mma(1);
  }

  // epilogue. C/D frag: col = lane&15, row = (lane>>4)*4 + e  [m89]
  if constexpr (EPI == 4) {
    constexpr float K2 = 0.045084834f;  // log2(e)/32
    u16* C = (u16*)out0 + (size_t)z * sCz;
    const float* cc = p0 + z * 2048;    // pre-scaled: c2 = c*K2
    float* rs = p1 + z * 2048;
    float psum[4][4] = {};
#pragma unroll
    for (int nh = 0; nh < 2; ++nh)
#pragma unroll
      for (int nf = 0; nf < 2; ++nf) {
        const int col = bn + wc * 64 + nh * 32 + nf * 16 + lr;
        const float cj2 = cc[col];
#pragma unroll
        for (int mf = 0; mf < 4; ++mf) {
          const int row = bm + wr * 64 + mf * 16 + lq * 4;
#pragma unroll
          for (int e = 0; e < 4; ++e) {
            const float pv = exp2f(fmaf(acc[mf][nh][nf][e], K2, cj2));
            C[(size_t)(row + e) * ldc + col] = f2bf(pv);
            psum[mf][e] += pv;
          }
        }
      }
#pragma unroll
    for (int off = 1; off <= 8; off <<= 1)
#pragma unroll
      for (int mf = 0; mf < 4; ++mf)
#pragma unroll
        for (int e = 0; e < 4; ++e)
          psum[mf][e] += __shfl_xor(psum[mf][e], off, 64);
    if (lr == 0) {
#pragma unroll
      for (int mf = 0; mf < 4; ++mf)
#pragma unroll
        for (int e = 0; e < 4; ++e)
          atomicAdd(&rs[bm + wr * 64 + mf * 16 + lq * 4 + e], psum[mf][e]);
    }
  } else if constexpr (EPI == 5) {
    float* C = (float*)out0 + (size_t)z * sCz;
    const float* rs = p1 + z * 2048;
#pragma unroll
    for (int nh = 0; nh < 2; ++nh)
#pragma unroll
      for (int nf = 0; nf < 2; ++nf) {
        const int col = bn + wc * 64 + nh * 32 + nf * 16 + lr;
#pragma unroll
        for (int mf = 0; mf < 4; ++mf) {
          const int row = bm + wr * 64 + mf * 16 + lq * 4;
#pragma unroll
          for (int e = 0; e < 4; ++e)
            C[(size_t)(row + e) * ldc + col] =
                acc[mf][nh][nf][e] / rs[row + e];
        }
      }
  } else {  // EPI 7: TV fused
    const int mat = bn >> 10;
    u16* T = (u16*)out0;
    u16* V = (u16*)out1;
#pragma unroll
    for (int nh = 0; nh < 2; ++nh)
#pragma unroll
      for (int nf = 0; nf < 2; ++nf) {
        const int oc = (bn + wc * 64 + nh * 32 + nf * 16 + lr) & 1023;
        if (mat == 0) {
#pragma unroll
          for (int mf = 0; mf < 4; ++mf) {
            const int row = bm + wr * 64 + mf * 16 + lq * 4;
#pragma unroll
            for (int e = 0; e < 4; ++e)
              T[(size_t)(row + e) * 1024 + oc] = f2bf(acc[mf][nh][nf][e]);
          }
        } else {
          const float bb2 = p2[oc];
#pragma unroll
          for (int mf = 0; mf < 4; ++mf) {
            const int row = bm + wr * 64 + mf * 16 + lq * 4;
            const int bz = row >> 11, sdx = row & 2047;
            ushort4 pk;
            pk.x = f2bf(acc[mf][nh][nf][0] + bb2);
            pk.y = f2bf(acc[mf][nh][nf][1] + bb2);
            pk.z = f2bf(acc[mf][nh][nf][2] + bb2);
            pk.w = f2bf(acc[mf][nh][nf][3] + bb2);
            *(ushort4*)&V[((size_t)bz * 1024 + oc) * 2048 + sdx] = pk;
          }
        }
      }
  }
}

// ---------------------------------------------------------------------------
// 128x128 2-phase core, split-K M partials (f32 slices).
// ---------------------------------------------------------------------------
__global__ __launch_bounds__(256) void gemmM(
    const u16* __restrict__ Abase, const u16* __restrict__ Btbase,
    float* __restrict__ out0, int Kd, int Kext, int ldc, long long sAz,
    long long sBz, long long sCz) {
  constexpr int ASZ = 16384;
  constexpr int BSZ = 16384;
  constexpr int BBASE = 2 * ASZ;
  __shared__ char lds[2 * ASZ + 3 * BSZ];

  const int tid = threadIdx.x;
  const int w = tid >> 6, l = tid & 63;
  const int wr = w >> 1, wc = w & 1;
  const int lq = l >> 4, lr = l & 15;
  const int bm = blockIdx.y * 128, bn = blockIdx.x * 128;
  const int z = blockIdx.z;
  const u16* A = Abase + (size_t)z * sAz;
  const u16* Bt = Btbase + (size_t)z * sBz;
  const int NT = Kext >> 6;

  const int kbp = ((tid & 7) ^ ((tid >> 3) & 7)) * 8;
  const int drow = tid >> 3;
  const u16* gA[4];
  const u16* gB[4];
#pragma unroll
  for (int u = 0; u < 4; ++u) {
    gA[u] = A + (size_t)(bm + u * 32 + drow) * Kd + kbp;
    gB[u] = Bt + (size_t)(bn + u * 32 + drow) * Kd + kbp;
  }

  auto stageA = [&](int kt) {
    char* d = lds + (kt & 1) * ASZ + tid * 16;
#pragma unroll
    for (int u = 0; u < 4; ++u) gload_lds16(gA[u] + kt * 64, d + u * 4096);
  };
  auto stageB = [&](int kt) {
    char* d = lds + BBASE + (kt % 3) * BSZ + tid * 16;
#pragma unroll
    for (int u = 0; u < 4; ++u) gload_lds16(gB[u] + kt * 64, d + u * 4096);
  };

  const int rA = wr * 64 + lr;
  const int rB0 = wc * 64 + lr;
  int aoff[2];
#pragma unroll
  for (int kh = 0; kh < 2; ++kh)
    aoff[kh] = rA * 128 + (((kh * 4 + lq) ^ (rA & 7)) << 4);

  f32x4 acc[4][2][2] = {};
  bf16x8 a[2][4];
  bf16x8 bb[2][2][2];

  auto rdA = [&](int kt) {
    const char* p = lds + (kt & 1) * ASZ;
#pragma unroll
    for (int kh = 0; kh < 2; ++kh)
#pragma unroll
      for (int mf = 0; mf < 4; ++mf)
        a[kh][mf] = *(const bf16x8*)(p + aoff[kh] + mf * 2048);
  };
  auto rdB = [&](int kt) {
    const char* p = lds + BBASE + (kt % 3) * BSZ;
#pragma unroll
    for (int nh = 0; nh < 2; ++nh) {
      const int rB = rB0 + nh * 32;
#pragma unroll
      for (int kh = 0; kh < 2; ++kh) {
        const int o = rB * 128 + (((kh * 4 + lq) ^ (rB & 7)) << 4);
#pragma unroll
        for (int nf = 0; nf < 2; ++nf)
          bb[nh][kh][nf] = *(const bf16x8*)(p + o + nf * 2048);
      }
    }
  };
  auto mma = [&](int kh) {
#pragma unroll
    for (int nh = 0; nh < 2; ++nh)
#pragma unroll
      for (int mf = 0; mf < 4; ++mf)
#pragma unroll
        for (int nf = 0; nf < 2; ++nf)
          acc[mf][nh][nf] = __builtin_amdgcn_mfma_f32_16x16x32_bf16(
              a[kh][mf], bb[nh][kh][nf], acc[mf][nh][nf], 0, 0, 0);
  };

  stageB(0);
  stageA(0);
  stageB(1);
  stageA(1);
  VMC(8);
  BAR();

  for (int t = 0; t < NT; ++t) {
    rdA(t);
    rdB(t);
    if (t + 2 < NT) stageB(t + 2);
    BAR();
    mma(0);
    if (t + 2 < NT) VMC(4); else VMC(0);
    BAR();
    if (t + 2 < NT) stageA(t + 2);
    mma(1);
  }

  float* C = out0 + (size_t)z * sCz;
#pragma unroll
  for (int nh = 0; nh < 2; ++nh)
#pragma unroll
    for (int nf = 0; nf < 2; ++nf) {
      const int col = bn + wc * 64 + nh * 32 + nf * 16 + lr;
#pragma unroll
      for (int mf = 0; mf < 4; ++mf) {
        const int row = bm + wr * 64 + mf * 16 + lq * 4;
#pragma unroll
        for (int e = 0; e < 4; ++e)
          C[(size_t)(row + e) * ldc + col] = acc[mf][nh][nf][e];
      }
    }
}

// ---------------------------------------------------------------------------
// prep: one dispatch, 256-thr blocks, flat bid ranges.
//   bid < 8192          : x f32 -> xb bf16 (4 f32/thread)
//   8192 <= bid < 11264 : W cast/transpose tiles (z = (bid-8192)/1024)
//   bid >= 11264        : vvec[d] = Wk[d,:].bq
// ---------------------------------------------------------------------------
__global__ __launch_bounds__(256) void prep(
    const float* __restrict__ x, const float* __restrict__ Wq,
    const float* __restrict__ Wk, const float* __restrict__ Wv,
    const float* __restrict__ bq, u16* __restrict__ xb,
    u16* __restrict__ Wqb, u16* __restrict__ Wkb, u16* __restrict__ WtTV,
    float* __restrict__ vvec) {
  const int bid = blockIdx.x;
  const int tid = threadIdx.x;
  if (bid < 8192) {
    const int i = bid * 256 + tid;
    const float4 v = ((const float4*)x)[i];
    ushort4 o;
    o.x = f2bf(v.x);
    o.y = f2bf(v.y);
    o.z = f2bf(v.z);
    o.w = f2bf(v.w);
    ((ushort4*)xb)[i] = o;
  } else if (bid < 11264) {
    const int b = bid - 8192;
    const int zz = b >> 10, t2 = b & 1023;
    const int k0 = (t2 >> 5) * 32, n0 = (t2 & 31) * 32;
    const int tx = tid & 31, ty0 = tid >> 5;
    if (zz == 2) {
      __shared__ float s[32][33];
#pragma unroll
      for (int r = 0; r < 4; ++r) {
        const int row = ty0 + 8 * r;
        s[row][tx] = Wv[(size_t)(k0 + row) * 1024 + n0 + tx];
      }
      __syncthreads();
#pragma unroll
      for (int r = 0; r < 4; ++r) {
        const int row = ty0 + 8 * r;
        WtTV[1048576 + (size_t)(n0 + row) * 1024 + k0 + tx] =
            f2bf(s[tx][row]);
      }
    } else {
      const float* W = zz ? Wk : Wq;
      u16* O = zz ? Wkb : Wqb;
#pragma unroll
      for (int r = 0; r < 4; ++r) {
        const size_t i = (size_t)(k0 + ty0 + 8 * r) * 1024 + n0 + tx;
        O[i] = f2bf(W[i]);
      }
    }
  } else {
    const int d = bid - 11264;
    const float4 wv = ((const float4*)(Wk + (size_t)d * 1024))[tid];
    const float4 bv = ((const float4*)bq)[tid];
    float p = wv.x * bv.x + wv.y * bv.y + wv.z * bv.z + wv.w * bv.w;
#pragma unroll
    for (int o = 32; o; o >>= 1) p += __shfl_xor(p, o, 64);
    __shared__ float red[4];
    if ((tid & 63) == 0) red[tid >> 6] = p;
    __syncthreads();
    if (tid == 0) vvec[d] = red[0] + red[1] + red[2] + red[3];
  }
}

// ---------------------------------------------------------------------------
// mck: merged mcast | cker (range-split).
// ---------------------------------------------------------------------------
__global__ __launch_bounds__(256) void mck(const float* __restrict__ Mf,
                                           u16* __restrict__ Mt,
                                           const u16* __restrict__ xb,
                                           const float* __restrict__ v,
                                           float* __restrict__ c,
                                           float* __restrict__ rowsum) {
  const int bid = blockIdx.x;
  const int tid = threadIdx.x;
  if (bid < 1024) {
    const int i = bid * 256 + tid;
    const float4 a = ((const float4*)Mf)[i];
    const float4 b = ((const float4*)(Mf + 1048576))[i];
    const float4 cc = ((const float4*)(Mf + 2097152))[i];
    const float4 d = ((const float4*)(Mf + 3145728))[i];
    ushort4 o;
    o.x = f2bf(a.x + b.x + cc.x + d.x);
    o.y = f2bf(a.y + b.y + cc.y + d.y);
    o.z = f2bf(a.z + b.z + cc.z + d.z);
    o.w = f2bf(a.w + b.w + cc.w + d.w);
    ((ushort4*)Mt)[i] = o;
  } else {
    const int b2 = bid - 1024;
    if (b2 < 32) rowsum[b2 * 256 + tid] = 0.f;
    const int j = b2 * 8 + (tid >> 5);
    const int lane = tid & 31;
    const u16* xr = xb + (size_t)j * 1024;
    float p = 0.f;
#pragma unroll
    for (int k = 0; k < 4; ++k) {
      const int g = k * 32 + lane;
      const uint4 u = ((const uint4*)xr)[g];
      const float4 v0 = ((const float4*)v)[g * 2];
      const float4 v1 = ((const float4*)v)[g * 2 + 1];
      p += bf2f(u.x & 0xffffu) * v0.x + bf2f(u.x >> 16) * v0.y +
           bf2f(u.y & 0xffffu) * v0.z + bf2f(u.y >> 16) * v0.w +
           bf2f(u.z & 0xffffu) * v1.x + bf2f(u.z >> 16) * v1.y +
           bf2f(u.w & 0xffffu) * v1.z + bf2f(u.w >> 16) * v1.w;
    }
#pragma unroll
    for (int o = 16; o; o >>= 1) p += __shfl_xor(p, o, 64);
    if (lane == 0) c[j] = p * 0.045084834f;  // pre-scale by log2(e)/32
  }
}

// ---------------------------------------------------------------------------
extern "C" void kernel_launch(void* const* d_in, const int* in_sizes, int n_in,
                              void* d_out, int out_size, void* d_ws,
                              size_t ws_size, hipStream_t stream) {
  const float* x = (const float*)d_in[0];
  const float* Wq = (const float*)d_in[1];
  const float* bq = (const float*)d_in[2];
  const float* Wk = (const float*)d_in[3];
  const float* Wv = (const float*)d_in[5];
  const float* bv = (const float*)d_in[6];
  float* out = (float*)d_out;
  char* ws = (char*)d_ws;

  u16* xb = (u16*)ws;                          // 16 MiB [8192][1024] bf16
  u16* WtTV = (u16*)(ws + 16777216);           // 4 MiB  [Mt;Wvt][1024] bf16
  u16* Wqb = (u16*)(ws + 20971520);            // 2 MiB
  u16* Wkb = (u16*)(ws + 23068672);            // 2 MiB
  float* vvec = (float*)(ws + 25165824);       // 4 KiB
  float* cvec = (float*)(ws + 25169920);       // 32 KiB [8192]
  float* rowsum = (float*)(ws + 25202688);     // 32 KiB [8192]
  float* Mf32 = (float*)(ws + 25235456);       // 16 MiB (4 slices); T aliases
  u16* T = (u16*)(ws + 25235456);              // 16 MiB [8192][1024] bf16
  u16* Vt = (u16*)(ws + 42012672);             // 16 MiB [4][1024][2048] bf16
  u16* SP = (u16*)(ws + 58789888);             // 32 MiB [4][2048][2048] bf16

  // 1) prep: x-cast | W casts/transpose | vvec = Wk.bq
  prep<<<12288, 256, 0, stream>>>(x, Wq, Wk, Wv, bq, xb, Wqb, Wkb, WtTV,
                                  vvec);

  // 2) Mt = (Wq Wk^T)^T  split-K (4 x 256) f32 slices
  gemmM<<<dim3(8, 8, 4), 256, 0, stream>>>(Wkb, Wqb, Mf32, 1024, 256, 1024,
                                           256LL, 256LL, 1048576LL);

  // 3) merged: Mt sum-cast | cvec (+rowsum zero)
  mck<<<2048, 256, 0, stream>>>(Mf32, WtTV, xb, vvec, cvec, rowsum);

  // 4) fused T = x.Mt^T (bn<1024) | V-proj transposed (bn>=1024); grid 512
  gemm2t<7><<<dim3(8, 64, 1), 512, 0, stream>>>(
      xb, WtTV, nullptr, nullptr, bv, T, Vt, 1024, 0, 0, 0, 0);

  // 5) P' = exp2(T.x^T*K2 + c2) bf16 + atomic rowsum; grid 512
  gemm2t<4><<<dim3(8, 16, 4), 512, 0, stream>>>(
      T, xb, cvec, rowsum, nullptr, SP, nullptr, 1024, 2048, 2097152LL,
      2097152LL, 4194304LL);

  // 6) out = (P'.V) / rowsum; grid 256
  gemm2t<5><<<dim3(4, 16, 4), 512, 0, stream>>>(
      SP, Vt, nullptr, rowsum, nullptr, out, nullptr, 2048, 1024, 4194304LL,
      2097152LL, 2097152LL);
}

// Round 17
// 156.984 us; speedup vs baseline: 1.2139x; 1.0487x over previous
//
#include <hip/hip_runtime.h>
#include <hip/hip_bf16.h>

typedef __attribute__((ext_vector_type(8))) short bf16x8;
typedef __attribute__((ext_vector_type(4))) float f32x4;
typedef unsigned short u16;

__device__ __forceinline__ u16 f2bf(float f) {
  unsigned int u = __builtin_bit_cast(unsigned int, f);
  u += 0x7fffu + ((u >> 16) & 1u);
  return (u16)(u >> 16);
}
__device__ __forceinline__ float bf2f(unsigned int h) {
  unsigned int u = h << 16;
  return __builtin_bit_cast(float, u);
}

__device__ __forceinline__ void gload_lds16(const void* g, void* l) {
  __builtin_amdgcn_global_load_lds(
      (const __attribute__((address_space(1))) void*)g,
      (__attribute__((address_space(3))) void*)l, 16, 0, 0);
}

#define BAR() __builtin_amdgcn_s_barrier()
#define VMC(N) asm volatile("s_waitcnt vmcnt(%0)" ::"n"(N) : "memory")

// ---------------------------------------------------------------------------
// gemm8q: m201-template probe (S GEMM only). 256x256 tile, 512 thr = 8
// waves (2 wr x 4 wc); per-wave 128x64; wave reads ONLY its A-half (wr)
// and B-half (wc>>1) — template fidelity points: M-quadrant-only phases
// (reads 12/4/4/4), B register-resident per K-tile (32 VGPR), exclusive
// A-half per wave, stage rotation q0/q1:A(u+1)->other buf, q2/q3:B(u+2)->
// own buf, ONE vmcnt(4)/K-tile at q3. Race audit: every staged region last
// read >=2 barriers before the stage issue; FIFO gate accounting verified
// (prologue 16 loads, vmcnt(8); steady 12 outstanding -> vmcnt(4)).
// EPI: S — P' = exp2(acc*K2 + c2[col]) bf16 + atomic rowsum.
// ---------------------------------------------------------------------------
__global__ __launch_bounds__(512, 2) void gemm8q(
    const u16* __restrict__ Abase, const u16* __restrict__ Btbase,
    const float* __restrict__ cc_all, float* __restrict__ rs_all,
    u16* __restrict__ outp, int Kd, int ldc, long long sAz, long long sBz,
    long long sCz) {
  constexpr int HSZ = 16384;       // half: 128 rows x 64 k x 2B
  constexpr int BUFSZ = 4 * HSZ;   // A0 A1 B0 B1
  __shared__ char lds[2 * BUFSZ];  // 131072 B

  // T1 bijective XCD remap (m204)
  const int gx = gridDim.x, gy = gridDim.y;
  const int nwg = gx * gy * gridDim.z;
  const int orig = blockIdx.x + gx * (blockIdx.y + gy * blockIdx.z);
  const int q = nwg >> 3, r = nwg & 7;
  const int xcd = orig & 7, loc = orig >> 3;
  const int wgid =
      (xcd < r ? xcd * (q + 1) : r * (q + 1) + (xcd - r) * q) + loc;
  const int bxi = wgid % gx;
  const int byi = (wgid / gx) % gy;
  const int z = wgid / (gx * gy);

  const int tid = threadIdx.x;
  const int w = tid >> 6, l = tid & 63;
  const int wr = w >> 2, wc = w & 3;
  const int lq = l >> 4, lr = l & 15;
  const int bm = byi * 256, bn = bxi * 256;
  const u16* A = Abase + (size_t)z * sAz;
  const u16* Bt = Btbase + (size_t)z * sBz;
  const int NT = Kd >> 6;

  // staging (dest linear tid*16 per half; source 16B-block pre-swizzled)
  const int kbp = ((tid & 7) ^ ((tid >> 3) & 7)) * 8;
  const int drow = tid >> 3;
  const u16* gA[2][2];
  const u16* gB[2][2];
#pragma unroll
  for (int h = 0; h < 2; ++h)
#pragma unroll
    for (int u = 0; u < 2; ++u) {
      gA[h][u] = A + (size_t)(bm + h * 128 + u * 64 + drow) * Kd + kbp;
      gB[h][u] = Bt + (size_t)(bn + h * 128 + u * 64 + drow) * Kd + kbp;
    }
  auto stageA = [&](int buf, int h, int kt) {
    char* d = lds + buf * BUFSZ + h * HSZ + tid * 16;
    gload_lds16(gA[h][0] + kt * 64, d);
    gload_lds16(gA[h][1] + kt * 64, d + 8192);
  };
  auto stageB = [&](int buf, int h, int kt) {
    char* d = lds + buf * BUFSZ + (2 + h) * HSZ + tid * 16;
    gload_lds16(gB[h][0] + kt * 64, d);
    gload_lds16(gB[h][1] + kt * 64, d + 8192);
  };

  const int ah = wr;              // exclusive A half
  const int bh = wc >> 1;         // exclusive B half
  const int bc0 = (wc & 1) * 64;  // local col base within B half
  const int sel = lr & 7;
  int koff[2];
#pragma unroll
  for (int kh = 0; kh < 2; ++kh) koff[kh] = (((kh * 4 + lq) ^ sel) << 4);

  f32x4 acc[8][4] = {};  // [mf][nf] = 128 VGPR
  bf16x8 bb[4][2];       // [nf][kh] resident per K-tile
  bf16x8 a[2][2];        // [mf2][kh] per phase

  // prologue: t0 full (8 loads), t1 full (8); wait t0
  stageA(0, 0, 0);
  stageA(0, 1, 0);
  stageB(0, 0, 0);
  stageB(0, 1, 0);
  stageA(1, 0, 1);
  stageA(1, 1, 1);
  stageB(1, 0, 1);
  stageB(1, 1, 1);
  VMC(8);
  BAR();

  for (int u = 0; u < NT; ++u) {
    const int buf = u & 1, obuf = buf ^ 1;
#pragma unroll
    for (int qp = 0; qp < 4; ++qp) {
      const char* pA = lds + buf * BUFSZ + ah * HSZ;
#pragma unroll
      for (int mf2 = 0; mf2 < 2; ++mf2)
#pragma unroll
        for (int kh = 0; kh < 2; ++kh)
          a[mf2][kh] = *(const bf16x8*)(pA + (qp * 32 + mf2 * 16 + lr) * 128 +
                                        koff[kh]);
      if (qp == 0) {
        const char* pB = lds + buf * BUFSZ + (2 + bh) * HSZ;
#pragma unroll
        for (int nf = 0; nf < 4; ++nf)
#pragma unroll
          for (int kh = 0; kh < 2; ++kh)
            bb[nf][kh] = *(const bf16x8*)(pB + (bc0 + nf * 16 + lr) * 128 +
                                          koff[kh]);
      }
      // stage rotation
      if (qp == 0 && u >= 1 && u + 1 < NT) stageA(obuf, 0, u + 1);
      if (qp == 1 && u >= 1 && u + 1 < NT) stageA(obuf, 1, u + 1);
      if (qp == 2 && u + 2 < NT) stageB(buf, 0, u + 2);
      if (qp == 3 && u + 2 < NT) stageB(buf, 1, u + 2);
      BAR();
      __builtin_amdgcn_s_setprio(1);
#pragma unroll
      for (int kh = 0; kh < 2; ++kh)
#pragma unroll
        for (int mf2 = 0; mf2 < 2; ++mf2)
#pragma unroll
          for (int nf = 0; nf < 4; ++nf)
            acc[qp * 2 + mf2][nf] = __builtin_amdgcn_mfma_f32_16x16x32_bf16(
                a[mf2][kh], bb[nf][kh], acc[qp * 2 + mf2][nf], 0, 0, 0);
      __builtin_amdgcn_s_setprio(0);
      if (qp == 3) {
        if (u + 2 < NT) {
          VMC(4);
        } else if (u + 1 < NT) {
          VMC(0);
        }
      }
      BAR();
    }
  }

  // epilogue: S — exp2 + rowsum. C/D frag col=lane&15, row=(lane>>4)*4+e.
  constexpr float K2 = 0.045084834f;  // log2(e)/32
  u16* C = outp + (size_t)z * sCz;
  const float* cc = cc_all + z * 2048;
  float* rs = rs_all + z * 2048;
#pragma unroll
  for (int mf = 0; mf < 8; ++mf) {
    const int row = bm + wr * 128 + mf * 16 + lq * 4;
    float ps[4] = {0.f, 0.f, 0.f, 0.f};
#pragma unroll
    for (int nf = 0; nf < 4; ++nf) {
      const int col = bn + wc * 64 + nf * 16 + lr;
      const float cj2 = cc[col];
#pragma unroll
      for (int e = 0; e < 4; ++e) {
        const float pv = exp2f(fmaf(acc[mf][nf][e], K2, cj2));
        C[(size_t)(row + e) * ldc + col] = f2bf(pv);
        ps[e] += pv;
      }
    }
#pragma unroll
    for (int off = 1; off <= 8; off <<= 1)
#pragma unroll
      for (int e = 0; e < 4; ++e) ps[e] += __shfl_xor(ps[e], off, 64);
    if (lr == 0) {
#pragma unroll
      for (int e = 0; e < 4; ++e) atomicAdd(&rs[row + e], ps[e]);
    }
  }
}

// ---------------------------------------------------------------------------
// r8-core 128x256 2-phase counted-vmcnt NT GEMM + T1 (proven; TV + PV).
// ---------------------------------------------------------------------------
template <int EPI>
__global__ __launch_bounds__(512, 2) void gemm2t(
    const u16* __restrict__ Abase, const u16* __restrict__ Btbase,
    const float* __restrict__ p0, float* __restrict__ p1,
    const float* __restrict__ p2, void* __restrict__ out0,
    void* __restrict__ out1, int Kd, int ldc, long long sAz, long long sBz,
    long long sCz) {
  constexpr int ASZ = 16384;
  constexpr int BSZ = 32768;
  constexpr int BBASE = 2 * ASZ;
  __shared__ char lds[2 * ASZ + 3 * BSZ];  // 131072 B

  const int gx = gridDim.x, gy = gridDim.y;
  const int nwg = gx * gy * gridDim.z;
  const int orig = blockIdx.x + gx * (blockIdx.y + gy * blockIdx.z);
  const int q = nwg >> 3, r = nwg & 7;
  const int xcd = orig & 7, loc = orig >> 3;
  const int wgid =
      (xcd < r ? xcd * (q + 1) : r * (q + 1) + (xcd - r) * q) + loc;
  const int bxi = wgid % gx;
  const int byi = (wgid / gx) % gy;
  const int z = wgid / (gx * gy);

  const int tid = threadIdx.x;
  const int w = tid >> 6, l = tid & 63;
  const int wr = w >> 2, wc = w & 3;
  const int lq = l >> 4, lr = l & 15;
  const int bm = byi * 128, bn = bxi * 256;
  const u16* A = Abase + (size_t)z * sAz;
  const u16* Bt = Btbase + (size_t)z * sBz;
  const int NT = Kd >> 6;

  const int kbp = ((tid & 7) ^ ((tid >> 3) & 7)) * 8;
  const int drow = tid >> 3;
  const u16* gA[2];
  const u16* gB[4];
#pragma unroll
  for (int u = 0; u < 2; ++u)
    gA[u] = A + (size_t)(bm + u * 64 + drow) * Kd + kbp;
#pragma unroll
  for (int u = 0; u < 4; ++u)
    gB[u] = Bt + (size_t)(bn + u * 64 + drow) * Kd + kbp;

  auto stageA = [&](int kt) {
    char* d = lds + (kt & 1) * ASZ + tid * 16;
#pragma unroll
    for (int u = 0; u < 2; ++u) gload_lds16(gA[u] + kt * 64, d + u * 8192);
  };
  auto stageB = [&](int kt) {
    char* d = lds + BBASE + (kt % 3) * BSZ + tid * 16;
#pragma unroll
    for (int u = 0; u < 4; ++u) gload_lds16(gB[u] + kt * 64, d + u * 8192);
  };

  const int rA = wr * 64 + lr;
  const int rB0 = wc * 64 + lr;
  int aoff[2];
#pragma unroll
  for (int kh = 0; kh < 2; ++kh)
    aoff[kh] = rA * 128 + (((kh * 4 + lq) ^ (rA & 7)) << 4);

  f32x4 acc[4][2][2] = {};
  bf16x8 a[2][4];
  bf16x8 bb[2][2][2];

  auto rdA = [&](int kt) {
    const char* p = lds + (kt & 1) * ASZ;
#pragma unroll
    for (int kh = 0; kh < 2; ++kh)
#pragma unroll
      for (int mf = 0; mf < 4; ++mf)
        a[kh][mf] = *(const bf16x8*)(p + aoff[kh] + mf * 2048);
  };
  auto rdB = [&](int kt) {
    const char* p = lds + BBASE + (kt % 3) * BSZ;
#pragma unroll
    for (int nh = 0; nh < 2; ++nh) {
      const int rB = rB0 + nh * 32;
#pragma unroll
      for (int kh = 0; kh < 2; ++kh) {
        const int o = rB * 128 + (((kh * 4 + lq) ^ (rB & 7)) << 4);
#pragma unroll
        for (int nf = 0; nf < 2; ++nf)
          bb[nh][kh][nf] = *(const bf16x8*)(p + o + nf * 2048);
      }
    }
  };
  auto mma = [&](int kh) {
    __builtin_amdgcn_s_setprio(1);
#pragma unroll
    for (int nh = 0; nh < 2; ++nh)
#pragma unroll
      for (int mf = 0; mf < 4; ++mf)
#pragma unroll
        for (int nf = 0; nf < 2; ++nf)
          acc[mf][nh][nf] = __builtin_amdgcn_mfma_f32_16x16x32_bf16(
              a[kh][mf], bb[nh][kh][nf], acc[mf][nh][nf], 0, 0, 0);
    __builtin_amdgcn_s_setprio(0);
  };

  stageB(0);
  stageA(0);
  stageB(1);
  stageA(1);
  VMC(6);
  BAR();

  for (int t = 0; t < NT; ++t) {
    rdA(t);
    rdB(t);
    if (t + 2 < NT) stageB(t + 2);
    BAR();
    mma(0);
    if (t + 2 < NT) VMC(4); else VMC(0);
    BAR();
    if (t + 2 < NT) stageA(t + 2);
    mma(1);
  }

  if constexpr (EPI == 5) {
    float* C = (float*)out0 + (size_t)z * sCz;
    const float* rs = p1 + z * 2048;
#pragma unroll
    for (int nh = 0; nh < 2; ++nh)
#pragma unroll
      for (int nf = 0; nf < 2; ++nf) {
        const int col = bn + wc * 64 + nh * 32 + nf * 16 + lr;
#pragma unroll
        for (int mf = 0; mf < 4; ++mf) {
          const int row = bm + wr * 64 + mf * 16 + lq * 4;
#pragma unroll
          for (int e = 0; e < 4; ++e)
            C[(size_t)(row + e) * ldc + col] =
                acc[mf][nh][nf][e] / rs[row + e];
        }
      }
  } else {  // EPI 7: TV fused
    const int mat = bn >> 10;
    u16* T = (u16*)out0;
    u16* V = (u16*)out1;
#pragma unroll
    for (int nh = 0; nh < 2; ++nh)
#pragma unroll
      for (int nf = 0; nf < 2; ++nf) {
        const int oc = (bn + wc * 64 + nh * 32 + nf * 16 + lr) & 1023;
        if (mat == 0) {
#pragma unroll
          for (int mf = 0; mf < 4; ++mf) {
            const int row = bm + wr * 64 + mf * 16 + lq * 4;
#pragma unroll
            for (int e = 0; e < 4; ++e)
              T[(size_t)(row + e) * 1024 + oc] = f2bf(acc[mf][nh][nf][e]);
          }
        } else {
          const float bb2 = p2[oc];
#pragma unroll
          for (int mf = 0; mf < 4; ++mf) {
            const int row = bm + wr * 64 + mf * 16 + lq * 4;
            const int bz = row >> 11, sdx = row & 2047;
            ushort4 pk;
            pk.x = f2bf(acc[mf][nh][nf][0] + bb2);
            pk.y = f2bf(acc[mf][nh][nf][1] + bb2);
            pk.z = f2bf(acc[mf][nh][nf][2] + bb2);
            pk.w = f2bf(acc[mf][nh][nf][3] + bb2);
            *(ushort4*)&V[((size_t)bz * 1024 + oc) * 2048 + sdx] = pk;
          }
        }
      }
  }
}

// ---------------------------------------------------------------------------
// 128x128 2-phase core, split-K M partials (f32 slices).
// ---------------------------------------------------------------------------
__global__ __launch_bounds__(256) void gemmM(
    const u16* __restrict__ Abase, const u16* __restrict__ Btbase,
    float* __restrict__ out0, int Kd, int Kext, int ldc, long long sAz,
    long long sBz, long long sCz) {
  constexpr int ASZ = 16384;
  constexpr int BSZ = 16384;
  constexpr int BBASE = 2 * ASZ;
  __shared__ char lds[2 * ASZ + 3 * BSZ];

  const int tid = threadIdx.x;
  const int w = tid >> 6, l = tid & 63;
  const int wr = w >> 1, wc = w & 1;
  const int lq = l >> 4, lr = l & 15;
  const int bm = blockIdx.y * 128, bn = blockIdx.x * 128;
  const int z = blockIdx.z;
  const u16* A = Abase + (size_t)z * sAz;
  const u16* Bt = Btbase + (size_t)z * sBz;
  const int NT = Kext >> 6;

  const int kbp = ((tid & 7) ^ ((tid >> 3) & 7)) * 8;
  const int drow = tid >> 3;
  const u16* gA[4];
  const u16* gB[4];
#pragma unroll
  for (int u = 0; u < 4; ++u) {
    gA[u] = A + (size_t)(bm + u * 32 + drow) * Kd + kbp;
    gB[u] = Bt + (size_t)(bn + u * 32 + drow) * Kd + kbp;
  }

  auto stageA = [&](int kt) {
    char* d = lds + (kt & 1) * ASZ + tid * 16;
#pragma unroll
    for (int u = 0; u < 4; ++u) gload_lds16(gA[u] + kt * 64, d + u * 4096);
  };
  auto stageB = [&](int kt) {
    char* d = lds + BBASE + (kt % 3) * BSZ + tid * 16;
#pragma unroll
    for (int u = 0; u < 4; ++u) gload_lds16(gB[u] + kt * 64, d + u * 4096);
  };

  const int rA = wr * 64 + lr;
  const int rB0 = wc * 64 + lr;
  int aoff[2];
#pragma unroll
  for (int kh = 0; kh < 2; ++kh)
    aoff[kh] = rA * 128 + (((kh * 4 + lq) ^ (rA & 7)) << 4);

  f32x4 acc[4][2][2] = {};
  bf16x8 a[2][4];
  bf16x8 bb[2][2][2];

  auto rdA = [&](int kt) {
    const char* p = lds + (kt & 1) * ASZ;
#pragma unroll
    for (int kh = 0; kh < 2; ++kh)
#pragma unroll
      for (int mf = 0; mf < 4; ++mf)
        a[kh][mf] = *(const bf16x8*)(p + aoff[kh] + mf * 2048);
  };
  auto rdB = [&](int kt) {
    const char* p = lds + BBASE + (kt % 3) * BSZ;
#pragma unroll
    for (int nh = 0; nh < 2; ++nh) {
      const int rB = rB0 + nh * 32;
#pragma unroll
      for (int kh = 0; kh < 2; ++kh) {
        const int o = rB * 128 + (((kh * 4 + lq) ^ (rB & 7)) << 4);
#pragma unroll
        for (int nf = 0; nf < 2; ++nf)
          bb[nh][kh][nf] = *(const bf16x8*)(p + o + nf * 2048);
      }
    }
  };
  auto mma = [&](int kh) {
#pragma unroll
    for (int nh = 0; nh < 2; ++nh)
#pragma unroll
      for (int mf = 0; mf < 4; ++mf)
#pragma unroll
        for (int nf = 0; nf < 2; ++nf)
          acc[mf][nh][nf] = __builtin_amdgcn_mfma_f32_16x16x32_bf16(
              a[kh][mf], bb[nh][kh][nf], acc[mf][nh][nf], 0, 0, 0);
  };

  stageB(0);
  stageA(0);
  stageB(1);
  stageA(1);
  VMC(8);
  BAR();

  for (int t = 0; t < NT; ++t) {
    rdA(t);
    rdB(t);
    if (t + 2 < NT) stageB(t + 2);
    BAR();
    mma(0);
    if (t + 2 < NT) VMC(4); else VMC(0);
    BAR();
    if (t + 2 < NT) stageA(t + 2);
    mma(1);
  }

  float* C = out0 + (size_t)z * sCz;
#pragma unroll
  for (int nh = 0; nh < 2; ++nh)
#pragma unroll
    for (int nf = 0; nf < 2; ++nf) {
      const int col = bn + wc * 64 + nh * 32 + nf * 16 + lr;
#pragma unroll
      for (int mf = 0; mf < 4; ++mf) {
        const int row = bm + wr * 64 + mf * 16 + lq * 4;
#pragma unroll
        for (int e = 0; e < 4; ++e)
          C[(size_t)(row + e) * ldc + col] = acc[mf][nh][nf][e];
      }
    }
}

// ---------------------------------------------------------------------------
// prep: one dispatch, 256-thr blocks, flat bid ranges.
// ---------------------------------------------------------------------------
__global__ __launch_bounds__(256) void prep(
    const float* __restrict__ x, const float* __restrict__ Wq,
    const float* __restrict__ Wk, const float* __restrict__ Wv,
    const float* __restrict__ bq, u16* __restrict__ xb,
    u16* __restrict__ Wqb, u16* __restrict__ Wkb, u16* __restrict__ WtTV,
    float* __restrict__ vvec) {
  const int bid = blockIdx.x;
  const int tid = threadIdx.x;
  if (bid < 8192) {
    const int i = bid * 256 + tid;
    const float4 v = ((const float4*)x)[i];
    ushort4 o;
    o.x = f2bf(v.x);
    o.y = f2bf(v.y);
    o.z = f2bf(v.z);
    o.w = f2bf(v.w);
    ((ushort4*)xb)[i] = o;
  } else if (bid < 11264) {
    const int b = bid - 8192;
    const int zz = b >> 10, t2 = b & 1023;
    const int k0 = (t2 >> 5) * 32, n0 = (t2 & 31) * 32;
    const int tx = tid & 31, ty0 = tid >> 5;
    if (zz == 2) {
      __shared__ float s[32][33];
#pragma unroll
      for (int r = 0; r < 4; ++r) {
        const int row = ty0 + 8 * r;
        s[row][tx] = Wv[(size_t)(k0 + row) * 1024 + n0 + tx];
      }
      __syncthreads();
#pragma unroll
      for (int r = 0; r < 4; ++r) {
        const int row = ty0 + 8 * r;
        WtTV[1048576 + (size_t)(n0 + row) * 1024 + k0 + tx] =
            f2bf(s[tx][row]);
      }
    } else {
      const float* W = zz ? Wk : Wq;
      u16* O = zz ? Wkb : Wqb;
#pragma unroll
      for (int r = 0; r < 4; ++r) {
        const size_t i = (size_t)(k0 + ty0 + 8 * r) * 1024 + n0 + tx;
        O[i] = f2bf(W[i]);
      }
    }
  } else {
    const int d = bid - 11264;
    const float4 wv = ((const float4*)(Wk + (size_t)d * 1024))[tid];
    const float4 bv = ((const float4*)bq)[tid];
    float p = wv.x * bv.x + wv.y * bv.y + wv.z * bv.z + wv.w * bv.w;
#pragma unroll
    for (int o = 32; o; o >>= 1) p += __shfl_xor(p, o, 64);
    __shared__ float red[4];
    if ((tid & 63) == 0) red[tid >> 6] = p;
    __syncthreads();
    if (tid == 0) vvec[d] = red[0] + red[1] + red[2] + red[3];
  }
}

// ---------------------------------------------------------------------------
// mck: merged mcast | cker (range-split).
// ---------------------------------------------------------------------------
__global__ __launch_bounds__(256) void mck(const float* __restrict__ Mf,
                                           u16* __restrict__ Mt,
                                           const u16* __restrict__ xb,
                                           const float* __restrict__ v,
                                           float* __restrict__ c,
                                           float* __restrict__ rowsum) {
  const int bid = blockIdx.x;
  const int tid = threadIdx.x;
  if (bid < 1024) {
    const int i = bid * 256 + tid;
    const float4 a = ((const float4*)Mf)[i];
    const float4 b = ((const float4*)(Mf + 1048576))[i];
    const float4 cc = ((const float4*)(Mf + 2097152))[i];
    const float4 d = ((const float4*)(Mf + 3145728))[i];
    ushort4 o;
    o.x = f2bf(a.x + b.x + cc.x + d.x);
    o.y = f2bf(a.y + b.y + cc.y + d.y);
    o.z = f2bf(a.z + b.z + cc.z + d.z);
    o.w = f2bf(a.w + b.w + cc.w + d.w);
    ((ushort4*)Mt)[i] = o;
  } else {
    const int b2 = bid - 1024;
    if (b2 < 32) rowsum[b2 * 256 + tid] = 0.f;
    const int j = b2 * 8 + (tid >> 5);
    const int lane = tid & 31;
    const u16* xr = xb + (size_t)j * 1024;
    float p = 0.f;
#pragma unroll
    for (int k = 0; k < 4; ++k) {
      const int g = k * 32 + lane;
      const uint4 u = ((const uint4*)xr)[g];
      const float4 v0 = ((const float4*)v)[g * 2];
      const float4 v1 = ((const float4*)v)[g * 2 + 1];
      p += bf2f(u.x & 0xffffu) * v0.x + bf2f(u.x >> 16) * v0.y +
           bf2f(u.y & 0xffffu) * v0.z + bf2f(u.y >> 16) * v0.w +
           bf2f(u.z & 0xffffu) * v1.x + bf2f(u.z >> 16) * v1.y +
           bf2f(u.w & 0xffffu) * v1.z + bf2f(u.w >> 16) * v1.w;
    }
#pragma unroll
    for (int o = 16; o; o >>= 1) p += __shfl_xor(p, o, 64);
    if (lane == 0) c[j] = p * 0.045084834f;  // pre-scale by log2(e)/32
  }
}

// ---------------------------------------------------------------------------
extern "C" void kernel_launch(void* const* d_in, const int* in_sizes, int n_in,
                              void* d_out, int out_size, void* d_ws,
                              size_t ws_size, hipStream_t stream) {
  const float* x = (const float*)d_in[0];
  const float* Wq = (const float*)d_in[1];
  const float* bq = (const float*)d_in[2];
  const float* Wk = (const float*)d_in[3];
  const float* Wv = (const float*)d_in[5];
  const float* bv = (const float*)d_in[6];
  float* out = (float*)d_out;
  char* ws = (char*)d_ws;

  u16* xb = (u16*)ws;                          // 16 MiB [8192][1024] bf16
  u16* WtTV = (u16*)(ws + 16777216);           // 4 MiB  [Mt;Wvt][1024] bf16
  u16* Wqb = (u16*)(ws + 20971520);            // 2 MiB
  u16* Wkb = (u16*)(ws + 23068672);            // 2 MiB
  float* vvec = (float*)(ws + 25165824);       // 4 KiB
  float* cvec = (float*)(ws + 25169920);       // 32 KiB [8192]
  float* rowsum = (float*)(ws + 25202688);     // 32 KiB [8192]
  float* Mf32 = (float*)(ws + 25235456);       // 16 MiB (4 slices); T aliases
  u16* T = (u16*)(ws + 25235456);              // 16 MiB [8192][1024] bf16
  u16* Vt = (u16*)(ws + 42012672);             // 16 MiB [4][1024][2048] bf16
  u16* SP = (u16*)(ws + 58789888);             // 32 MiB [4][2048][2048] bf16

  // 1) prep: x-cast | W casts/transpose | vvec = Wk.bq
  prep<<<12288, 256, 0, stream>>>(x, Wq, Wk, Wv, bq, xb, Wqb, Wkb, WtTV,
                                  vvec);

  // 2) Mt = (Wq Wk^T)^T  split-K (4 x 256) f32 slices
  gemmM<<<dim3(8, 8, 4), 256, 0, stream>>>(Wkb, Wqb, Mf32, 1024, 256, 1024,
                                           256LL, 256LL, 1048576LL);

  // 3) merged: Mt sum-cast | cvec (+rowsum zero)
  mck<<<2048, 256, 0, stream>>>(Mf32, WtTV, xb, vvec, cvec, rowsum);

  // 4) fused T = x.Mt^T (bn<1024) | V-proj transposed (bn>=1024); grid 512
  gemm2t<7><<<dim3(8, 64, 1), 512, 0, stream>>>(
      xb, WtTV, nullptr, nullptr, bv, T, Vt, 1024, 0, 0, 0, 0);

  // 5) P' = exp2(T.x^T*K2 + c2) bf16 + atomic rowsum — m201-template probe
  gemm8q<<<dim3(8, 8, 4), 512, 0, stream>>>(T, xb, cvec, rowsum, SP, 1024,
                                            2048, 2097152LL, 2097152LL,
                                            4194304LL);

  // 6) out = (P'.V) / rowsum; grid 256
  gemm2t<5><<<dim3(4, 16, 4), 512, 0, stream>>>(
      SP, Vt, nullptr, rowsum, nullptr, out, nullptr, 2048, 1024, 4194304LL,
      2097152LL, 2097152LL);
}

// Round 18
// 151.008 us; speedup vs baseline: 1.2620x; 1.0396x over previous
//
#include <hip/hip_runtime.h>
#include <hip/hip_bf16.h>

typedef __attribute__((ext_vector_type(8))) short bf16x8;
typedef __attribute__((ext_vector_type(4))) float f32x4;
typedef unsigned short u16;

__device__ __forceinline__ u16 f2bf(float f) {
  unsigned int u = __builtin_bit_cast(unsigned int, f);
  u += 0x7fffu + ((u >> 16) & 1u);
  return (u16)(u >> 16);
}
__device__ __forceinline__ float bf2f(unsigned int h) {
  unsigned int u = h << 16;
  return __builtin_bit_cast(float, u);
}

__device__ __forceinline__ void gload_lds16(const void* g, void* l) {
  __builtin_amdgcn_global_load_lds(
      (const __attribute__((address_space(1))) void*)g,
      (__attribute__((address_space(3))) void*)l, 16, 0, 0);
}

#define BAR() __builtin_amdgcn_s_barrier()
#define VMC(N) asm volatile("s_waitcnt vmcnt(%0)" ::"n"(N) : "memory")

// ---------------------------------------------------------------------------
// gemm8q: m201-style 256x256 8-phase core (verified r17: S -11%).
// 512 thr = 8 waves (2 wr x 4 wc); per-wave 128x64; wave reads ONLY its
// A-half (wr) / B-half (wc>>1). M-quadrant phases (reads 12/4/4/4), B
// register-resident per K-tile, stage rotation q0/q1:A(u+1)->other buf,
// q2/q3:B(u+2)->own buf, ONE vmcnt(4)/K-tile at q3 (FIFO audit r16).
// LDS swizzle: 16B-block ^= (row&7) (0 conflicts, r1-r17). T1 XCD remap.
// EPI 4: S — P' = exp2(acc*K2 + c2[col]) bf16 + atomic rowsum (p0=c2,p1=rs)
// EPI 7: TV — fused T (bf16, bn<1024) | V^T (+p2 bias)
// ---------------------------------------------------------------------------
template <int EPI>
__global__ __launch_bounds__(512, 2) void gemm8q(
    const u16* __restrict__ Abase, const u16* __restrict__ Btbase,
    const float* __restrict__ p0, float* __restrict__ p1,
    const float* __restrict__ p2, void* __restrict__ out0,
    void* __restrict__ out1, int Kd, int ldc, long long sAz, long long sBz,
    long long sCz) {
  constexpr int HSZ = 16384;       // half: 128 rows x 64 k x 2B
  constexpr int BUFSZ = 4 * HSZ;   // A0 A1 B0 B1
  __shared__ char lds[2 * BUFSZ];  // 131072 B

  // T1 bijective XCD remap (m204)
  const int gx = gridDim.x, gy = gridDim.y;
  const int nwg = gx * gy * gridDim.z;
  const int orig = blockIdx.x + gx * (blockIdx.y + gy * blockIdx.z);
  const int q = nwg >> 3, r = nwg & 7;
  const int xcd = orig & 7, loc = orig >> 3;
  const int wgid =
      (xcd < r ? xcd * (q + 1) : r * (q + 1) + (xcd - r) * q) + loc;
  const int bxi = wgid % gx;
  const int byi = (wgid / gx) % gy;
  const int z = wgid / (gx * gy);

  const int tid = threadIdx.x;
  const int w = tid >> 6, l = tid & 63;
  const int wr = w >> 2, wc = w & 3;
  const int lq = l >> 4, lr = l & 15;
  const int bm = byi * 256, bn = bxi * 256;
  const u16* A = Abase + (size_t)z * sAz;
  const u16* Bt = Btbase + (size_t)z * sBz;
  const int NT = Kd >> 6;

  const int kbp = ((tid & 7) ^ ((tid >> 3) & 7)) * 8;
  const int drow = tid >> 3;
  const u16* gA[2][2];
  const u16* gB[2][2];
#pragma unroll
  for (int h = 0; h < 2; ++h)
#pragma unroll
    for (int u = 0; u < 2; ++u) {
      gA[h][u] = A + (size_t)(bm + h * 128 + u * 64 + drow) * Kd + kbp;
      gB[h][u] = Bt + (size_t)(bn + h * 128 + u * 64 + drow) * Kd + kbp;
    }
  auto stageA = [&](int buf, int h, int kt) {
    char* d = lds + buf * BUFSZ + h * HSZ + tid * 16;
    gload_lds16(gA[h][0] + kt * 64, d);
    gload_lds16(gA[h][1] + kt * 64, d + 8192);
  };
  auto stageB = [&](int buf, int h, int kt) {
    char* d = lds + buf * BUFSZ + (2 + h) * HSZ + tid * 16;
    gload_lds16(gB[h][0] + kt * 64, d);
    gload_lds16(gB[h][1] + kt * 64, d + 8192);
  };

  const int ah = wr;              // exclusive A half
  const int bh = wc >> 1;         // exclusive B half
  const int bc0 = (wc & 1) * 64;  // local col base within B half
  const int sel = lr & 7;
  int koff[2];
#pragma unroll
  for (int kh = 0; kh < 2; ++kh) koff[kh] = (((kh * 4 + lq) ^ sel) << 4);

  f32x4 acc[8][4] = {};  // [mf][nf]
  bf16x8 bb[4][2];       // [nf][kh] resident per K-tile
  bf16x8 a[2][2];        // [mf2][kh] per phase

  stageA(0, 0, 0);
  stageA(0, 1, 0);
  stageB(0, 0, 0);
  stageB(0, 1, 0);
  stageA(1, 0, 1);
  stageA(1, 1, 1);
  stageB(1, 0, 1);
  stageB(1, 1, 1);
  VMC(8);
  BAR();

  for (int u = 0; u < NT; ++u) {
    const int buf = u & 1, obuf = buf ^ 1;
#pragma unroll
    for (int qp = 0; qp < 4; ++qp) {
      const char* pA = lds + buf * BUFSZ + ah * HSZ;
#pragma unroll
      for (int mf2 = 0; mf2 < 2; ++mf2)
#pragma unroll
        for (int kh = 0; kh < 2; ++kh)
          a[mf2][kh] = *(const bf16x8*)(pA + (qp * 32 + mf2 * 16 + lr) * 128 +
                                        koff[kh]);
      if (qp == 0) {
        const char* pB = lds + buf * BUFSZ + (2 + bh) * HSZ;
#pragma unroll
        for (int nf = 0; nf < 4; ++nf)
#pragma unroll
          for (int kh = 0; kh < 2; ++kh)
            bb[nf][kh] = *(const bf16x8*)(pB + (bc0 + nf * 16 + lr) * 128 +
                                          koff[kh]);
      }
      if (qp == 0 && u >= 1 && u + 1 < NT) stageA(obuf, 0, u + 1);
      if (qp == 1 && u >= 1 && u + 1 < NT) stageA(obuf, 1, u + 1);
      if (qp == 2 && u + 2 < NT) stageB(buf, 0, u + 2);
      if (qp == 3 && u + 2 < NT) stageB(buf, 1, u + 2);
      BAR();
      __builtin_amdgcn_s_setprio(1);
#pragma unroll
      for (int kh = 0; kh < 2; ++kh)
#pragma unroll
        for (int mf2 = 0; mf2 < 2; ++mf2)
#pragma unroll
          for (int nf = 0; nf < 4; ++nf)
            acc[qp * 2 + mf2][nf] = __builtin_amdgcn_mfma_f32_16x16x32_bf16(
                a[mf2][kh], bb[nf][kh], acc[qp * 2 + mf2][nf], 0, 0, 0);
      __builtin_amdgcn_s_setprio(0);
      if (qp == 3) {
        if (u + 2 < NT) {
          VMC(4);
        } else if (u + 1 < NT) {
          VMC(0);
        }
      }
      BAR();
    }
  }

  // epilogue. C/D frag: col = lane&15, row = (lane>>4)*4 + e  [m89]
  if constexpr (EPI == 4) {
    constexpr float K2 = 0.045084834f;  // log2(e)/32
    u16* C = (u16*)out0 + (size_t)z * sCz;
    const float* cc = p0 + z * 2048;
    float* rs = p1 + z * 2048;
#pragma unroll
    for (int mf = 0; mf < 8; ++mf) {
      const int row = bm + wr * 128 + mf * 16 + lq * 4;
      float ps[4] = {0.f, 0.f, 0.f, 0.f};
#pragma unroll
      for (int nf = 0; nf < 4; ++nf) {
        const int col = bn + wc * 64 + nf * 16 + lr;
        const float cj2 = cc[col];
#pragma unroll
        for (int e = 0; e < 4; ++e) {
          const float pv = exp2f(fmaf(acc[mf][nf][e], K2, cj2));
          C[(size_t)(row + e) * ldc + col] = f2bf(pv);
          ps[e] += pv;
        }
      }
#pragma unroll
      for (int off = 1; off <= 8; off <<= 1)
#pragma unroll
        for (int e = 0; e < 4; ++e) ps[e] += __shfl_xor(ps[e], off, 64);
      if (lr == 0) {
#pragma unroll
        for (int e = 0; e < 4; ++e) atomicAdd(&rs[row + e], ps[e]);
      }
    }
  } else {  // EPI 7: TV fused
    const int mat = bn >> 10;
    u16* T = (u16*)out0;
    u16* V = (u16*)out1;
#pragma unroll
    for (int nf = 0; nf < 4; ++nf) {
      const int oc = (bn + wc * 64 + nf * 16 + lr) & 1023;
      if (mat == 0) {
#pragma unroll
        for (int mf = 0; mf < 8; ++mf) {
          const int row = bm + wr * 128 + mf * 16 + lq * 4;
#pragma unroll
          for (int e = 0; e < 4; ++e)
            T[(size_t)(row + e) * 1024 + oc] = f2bf(acc[mf][nf][e]);
        }
      } else {
        const float bb2 = p2[oc];
#pragma unroll
        for (int mf = 0; mf < 8; ++mf) {
          const int row = bm + wr * 128 + mf * 16 + lq * 4;
          const int bz = row >> 11, sdx = row & 2047;
          ushort4 pk;
          pk.x = f2bf(acc[mf][nf][0] + bb2);
          pk.y = f2bf(acc[mf][nf][1] + bb2);
          pk.z = f2bf(acc[mf][nf][2] + bb2);
          pk.w = f2bf(acc[mf][nf][3] + bb2);
          *(ushort4*)&V[((size_t)bz * 1024 + oc) * 2048 + sdx] = pk;
        }
      }
    }
  }
}

// ---------------------------------------------------------------------------
// r8-core 128x256 2-phase counted-vmcnt NT GEMM + T1 (proven; PV).
// EPI 5: PV — f32 out / rowsum (p1=rs).
// ---------------------------------------------------------------------------
template <int EPI>
__global__ __launch_bounds__(512, 2) void gemm2t(
    const u16* __restrict__ Abase, const u16* __restrict__ Btbase,
    const float* __restrict__ p0, float* __restrict__ p1,
    const float* __restrict__ p2, void* __restrict__ out0,
    void* __restrict__ out1, int Kd, int ldc, long long sAz, long long sBz,
    long long sCz) {
  constexpr int ASZ = 16384;
  constexpr int BSZ = 32768;
  constexpr int BBASE = 2 * ASZ;
  __shared__ char lds[2 * ASZ + 3 * BSZ];  // 131072 B

  const int gx = gridDim.x, gy = gridDim.y;
  const int nwg = gx * gy * gridDim.z;
  const int orig = blockIdx.x + gx * (blockIdx.y + gy * blockIdx.z);
  const int q = nwg >> 3, r = nwg & 7;
  const int xcd = orig & 7, loc = orig >> 3;
  const int wgid =
      (xcd < r ? xcd * (q + 1) : r * (q + 1) + (xcd - r) * q) + loc;
  const int bxi = wgid % gx;
  const int byi = (wgid / gx) % gy;
  const int z = wgid / (gx * gy);

  const int tid = threadIdx.x;
  const int w = tid >> 6, l = tid & 63;
  const int wr = w >> 2, wc = w & 3;
  const int lq = l >> 4, lr = l & 15;
  const int bm = byi * 128, bn = bxi * 256;
  const u16* A = Abase + (size_t)z * sAz;
  const u16* Bt = Btbase + (size_t)z * sBz;
  const int NT = Kd >> 6;

  const int kbp = ((tid & 7) ^ ((tid >> 3) & 7)) * 8;
  const int drow = tid >> 3;
  const u16* gA[2];
  const u16* gB[4];
#pragma unroll
  for (int u = 0; u < 2; ++u)
    gA[u] = A + (size_t)(bm + u * 64 + drow) * Kd + kbp;
#pragma unroll
  for (int u = 0; u < 4; ++u)
    gB[u] = Bt + (size_t)(bn + u * 64 + drow) * Kd + kbp;

  auto stageA = [&](int kt) {
    char* d = lds + (kt & 1) * ASZ + tid * 16;
#pragma unroll
    for (int u = 0; u < 2; ++u) gload_lds16(gA[u] + kt * 64, d + u * 8192);
  };
  auto stageB = [&](int kt) {
    char* d = lds + BBASE + (kt % 3) * BSZ + tid * 16;
#pragma unroll
    for (int u = 0; u < 4; ++u) gload_lds16(gB[u] + kt * 64, d + u * 8192);
  };

  const int rA = wr * 64 + lr;
  const int rB0 = wc * 64 + lr;
  int aoff[2];
#pragma unroll
  for (int kh = 0; kh < 2; ++kh)
    aoff[kh] = rA * 128 + (((kh * 4 + lq) ^ (rA & 7)) << 4);

  f32x4 acc[4][2][2] = {};
  bf16x8 a[2][4];
  bf16x8 bb[2][2][2];

  auto rdA = [&](int kt) {
    const char* p = lds + (kt & 1) * ASZ;
#pragma unroll
    for (int kh = 0; kh < 2; ++kh)
#pragma unroll
      for (int mf = 0; mf < 4; ++mf)
        a[kh][mf] = *(const bf16x8*)(p + aoff[kh] + mf * 2048);
  };
  auto rdB = [&](int kt) {
    const char* p = lds + BBASE + (kt % 3) * BSZ;
#pragma unroll
    for (int nh = 0; nh < 2; ++nh) {
      const int rB = rB0 + nh * 32;
#pragma unroll
      for (int kh = 0; kh < 2; ++kh) {
        const int o = rB * 128 + (((kh * 4 + lq) ^ (rB & 7)) << 4);
#pragma unroll
        for (int nf = 0; nf < 2; ++nf)
          bb[nh][kh][nf] = *(const bf16x8*)(p + o + nf * 2048);
      }
    }
  };
  auto mma = [&](int kh) {
    __builtin_amdgcn_s_setprio(1);
#pragma unroll
    for (int nh = 0; nh < 2; ++nh)
#pragma unroll
      for (int mf = 0; mf < 4; ++mf)
#pragma unroll
        for (int nf = 0; nf < 2; ++nf)
          acc[mf][nh][nf] = __builtin_amdgcn_mfma_f32_16x16x32_bf16(
              a[kh][mf], bb[nh][kh][nf], acc[mf][nh][nf], 0, 0, 0);
    __builtin_amdgcn_s_setprio(0);
  };

  stageB(0);
  stageA(0);
  stageB(1);
  stageA(1);
  VMC(6);
  BAR();

  for (int t = 0; t < NT; ++t) {
    rdA(t);
    rdB(t);
    if (t + 2 < NT) stageB(t + 2);
    BAR();
    mma(0);
    if (t + 2 < NT) VMC(4); else VMC(0);
    BAR();
    if (t + 2 < NT) stageA(t + 2);
    mma(1);
  }

  float* C = (float*)out0 + (size_t)z * sCz;
  const float* rs = p1 + z * 2048;
#pragma unroll
  for (int nh = 0; nh < 2; ++nh)
#pragma unroll
    for (int nf = 0; nf < 2; ++nf) {
      const int col = bn + wc * 64 + nh * 32 + nf * 16 + lr;
#pragma unroll
      for (int mf = 0; mf < 4; ++mf) {
        const int row = bm + wr * 64 + mf * 16 + lq * 4;
#pragma unroll
        for (int e = 0; e < 4; ++e)
          C[(size_t)(row + e) * ldc + col] = acc[mf][nh][nf][e] / rs[row + e];
      }
    }
}

// ---------------------------------------------------------------------------
// 128x128 2-phase core, split-K M partials (f32 slices).
// ---------------------------------------------------------------------------
__global__ __launch_bounds__(256) void gemmM(
    const u16* __restrict__ Abase, const u16* __restrict__ Btbase,
    float* __restrict__ out0, int Kd, int Kext, int ldc, long long sAz,
    long long sBz, long long sCz) {
  constexpr int ASZ = 16384;
  constexpr int BSZ = 16384;
  constexpr int BBASE = 2 * ASZ;
  __shared__ char lds[2 * ASZ + 3 * BSZ];

  const int tid = threadIdx.x;
  const int w = tid >> 6, l = tid & 63;
  const int wr = w >> 1, wc = w & 1;
  const int lq = l >> 4, lr = l & 15;
  const int bm = blockIdx.y * 128, bn = blockIdx.x * 128;
  const int z = blockIdx.z;
  const u16* A = Abase + (size_t)z * sAz;
  const u16* Bt = Btbase + (size_t)z * sBz;
  const int NT = Kext >> 6;

  const int kbp = ((tid & 7) ^ ((tid >> 3) & 7)) * 8;
  const int drow = tid >> 3;
  const u16* gA[4];
  const u16* gB[4];
#pragma unroll
  for (int u = 0; u < 4; ++u) {
    gA[u] = A + (size_t)(bm + u * 32 + drow) * Kd + kbp;
    gB[u] = Bt + (size_t)(bn + u * 32 + drow) * Kd + kbp;
  }

  auto stageA = [&](int kt) {
    char* d = lds + (kt & 1) * ASZ + tid * 16;
#pragma unroll
    for (int u = 0; u < 4; ++u) gload_lds16(gA[u] + kt * 64, d + u * 4096);
  };
  auto stageB = [&](int kt) {
    char* d = lds + BBASE + (kt % 3) * BSZ + tid * 16;
#pragma unroll
    for (int u = 0; u < 4; ++u) gload_lds16(gB[u] + kt * 64, d + u * 4096);
  };

  const int rA = wr * 64 + lr;
  const int rB0 = wc * 64 + lr;
  int aoff[2];
#pragma unroll
  for (int kh = 0; kh < 2; ++kh)
    aoff[kh] = rA * 128 + (((kh * 4 + lq) ^ (rA & 7)) << 4);

  f32x4 acc[4][2][2] = {};
  bf16x8 a[2][4];
  bf16x8 bb[2][2][2];

  auto rdA = [&](int kt) {
    const char* p = lds + (kt & 1) * ASZ;
#pragma unroll
    for (int kh = 0; kh < 2; ++kh)
#pragma unroll
      for (int mf = 0; mf < 4; ++mf)
        a[kh][mf] = *(const bf16x8*)(p + aoff[kh] + mf * 2048);
  };
  auto rdB = [&](int kt) {
    const char* p = lds + BBASE + (kt % 3) * BSZ;
#pragma unroll
    for (int nh = 0; nh < 2; ++nh) {
      const int rB = rB0 + nh * 32;
#pragma unroll
      for (int kh = 0; kh < 2; ++kh) {
        const int o = rB * 128 + (((kh * 4 + lq) ^ (rB & 7)) << 4);
#pragma unroll
        for (int nf = 0; nf < 2; ++nf)
          bb[nh][kh][nf] = *(const bf16x8*)(p + o + nf * 2048);
      }
    }
  };
  auto mma = [&](int kh) {
#pragma unroll
    for (int nh = 0; nh < 2; ++nh)
#pragma unroll
      for (int mf = 0; mf < 4; ++mf)
#pragma unroll
        for (int nf = 0; nf < 2; ++nf)
          acc[mf][nh][nf] = __builtin_amdgcn_mfma_f32_16x16x32_bf16(
              a[kh][mf], bb[nh][kh][nf], acc[mf][nh][nf], 0, 0, 0);
  };

  stageB(0);
  stageA(0);
  stageB(1);
  stageA(1);
  VMC(8);
  BAR();

  for (int t = 0; t < NT; ++t) {
    rdA(t);
    rdB(t);
    if (t + 2 < NT) stageB(t + 2);
    BAR();
    mma(0);
    if (t + 2 < NT) VMC(4); else VMC(0);
    BAR();
    if (t + 2 < NT) stageA(t + 2);
    mma(1);
  }

  float* C = out0 + (size_t)z * sCz;
#pragma unroll
  for (int nh = 0; nh < 2; ++nh)
#pragma unroll
    for (int nf = 0; nf < 2; ++nf) {
      const int col = bn + wc * 64 + nh * 32 + nf * 16 + lr;
#pragma unroll
      for (int mf = 0; mf < 4; ++mf) {
        const int row = bm + wr * 64 + mf * 16 + lq * 4;
#pragma unroll
        for (int e = 0; e < 4; ++e)
          C[(size_t)(row + e) * ldc + col] = acc[mf][nh][nf][e];
      }
    }
}

// ---------------------------------------------------------------------------
// prep: one dispatch, 256-thr blocks, flat bid ranges.
// ---------------------------------------------------------------------------
__global__ __launch_bounds__(256) void prep(
    const float* __restrict__ x, const float* __restrict__ Wq,
    const float* __restrict__ Wk, const float* __restrict__ Wv,
    const float* __restrict__ bq, u16* __restrict__ xb,
    u16* __restrict__ Wqb, u16* __restrict__ Wkb, u16* __restrict__ WtTV,
    float* __restrict__ vvec) {
  const int bid = blockIdx.x;
  const int tid = threadIdx.x;
  if (bid < 8192) {
    const int i = bid * 256 + tid;
    const float4 v = ((const float4*)x)[i];
    ushort4 o;
    o.x = f2bf(v.x);
    o.y = f2bf(v.y);
    o.z = f2bf(v.z);
    o.w = f2bf(v.w);
    ((ushort4*)xb)[i] = o;
  } else if (bid < 11264) {
    const int b = bid - 8192;
    const int zz = b >> 10, t2 = b & 1023;
    const int k0 = (t2 >> 5) * 32, n0 = (t2 & 31) * 32;
    const int tx = tid & 31, ty0 = tid >> 5;
    if (zz == 2) {
      __shared__ float s[32][33];
#pragma unroll
      for (int r = 0; r < 4; ++r) {
        const int row = ty0 + 8 * r;
        s[row][tx] = Wv[(size_t)(k0 + row) * 1024 + n0 + tx];
      }
      __syncthreads();
#pragma unroll
      for (int r = 0; r < 4; ++r) {
        const int row = ty0 + 8 * r;
        WtTV[1048576 + (size_t)(n0 + row) * 1024 + k0 + tx] =
            f2bf(s[tx][row]);
      }
    } else {
      const float* W = zz ? Wk : Wq;
      u16* O = zz ? Wkb : Wqb;
#pragma unroll
      for (int r = 0; r < 4; ++r) {
        const size_t i = (size_t)(k0 + ty0 + 8 * r) * 1024 + n0 + tx;
        O[i] = f2bf(W[i]);
      }
    }
  } else {
    const int d = bid - 11264;
    const float4 wv = ((const float4*)(Wk + (size_t)d * 1024))[tid];
    const float4 bv = ((const float4*)bq)[tid];
    float p = wv.x * bv.x + wv.y * bv.y + wv.z * bv.z + wv.w * bv.w;
#pragma unroll
    for (int o = 32; o; o >>= 1) p += __shfl_xor(p, o, 64);
    __shared__ float red[4];
    if ((tid & 63) == 0) red[tid >> 6] = p;
    __syncthreads();
    if (tid == 0) vvec[d] = red[0] + red[1] + red[2] + red[3];
  }
}

// ---------------------------------------------------------------------------
// mck: merged mcast | cker (range-split).
// ---------------------------------------------------------------------------
__global__ __launch_bounds__(256) void mck(const float* __restrict__ Mf,
                                           u16* __restrict__ Mt,
                                           const u16* __restrict__ xb,
                                           const float* __restrict__ v,
                                           float* __restrict__ c,
                                           float* __restrict__ rowsum) {
  const int bid = blockIdx.x;
  const int tid = threadIdx.x;
  if (bid < 1024) {
    const int i = bid * 256 + tid;
    const float4 a = ((const float4*)Mf)[i];
    const float4 b = ((const float4*)(Mf + 1048576))[i];
    const float4 cc = ((const float4*)(Mf + 2097152))[i];
    const float4 d = ((const float4*)(Mf + 3145728))[i];
    ushort4 o;
    o.x = f2bf(a.x + b.x + cc.x + d.x);
    o.y = f2bf(a.y + b.y + cc.y + d.y);
    o.z = f2bf(a.z + b.z + cc.z + d.z);
    o.w = f2bf(a.w + b.w + cc.w + d.w);
    ((ushort4*)Mt)[i] = o;
  } else {
    const int b2 = bid - 1024;
    if (b2 < 32) rowsum[b2 * 256 + tid] = 0.f;
    const int j = b2 * 8 + (tid >> 5);
    const int lane = tid & 31;
    const u16* xr = xb + (size_t)j * 1024;
    float p = 0.f;
#pragma unroll
    for (int k = 0; k < 4; ++k) {
      const int g = k * 32 + lane;
      const uint4 u = ((const uint4*)xr)[g];
      const float4 v0 = ((const float4*)v)[g * 2];
      const float4 v1 = ((const float4*)v)[g * 2 + 1];
      p += bf2f(u.x & 0xffffu) * v0.x + bf2f(u.x >> 16) * v0.y +
           bf2f(u.y & 0xffffu) * v0.z + bf2f(u.y >> 16) * v0.w +
           bf2f(u.z & 0xffffu) * v1.x + bf2f(u.z >> 16) * v1.y +
           bf2f(u.w & 0xffffu) * v1.z + bf2f(u.w >> 16) * v1.w;
    }
#pragma unroll
    for (int o = 16; o; o >>= 1) p += __shfl_xor(p, o, 64);
    if (lane == 0) c[j] = p * 0.045084834f;  // pre-scale by log2(e)/32
  }
}

// ---------------------------------------------------------------------------
extern "C" void kernel_launch(void* const* d_in, const int* in_sizes, int n_in,
                              void* d_out, int out_size, void* d_ws,
                              size_t ws_size, hipStream_t stream) {
  const float* x = (const float*)d_in[0];
  const float* Wq = (const float*)d_in[1];
  const float* bq = (const float*)d_in[2];
  const float* Wk = (const float*)d_in[3];
  const float* Wv = (const float*)d_in[5];
  const float* bv = (const float*)d_in[6];
  float* out = (float*)d_out;
  char* ws = (char*)d_ws;

  u16* xb = (u16*)ws;                          // 16 MiB [8192][1024] bf16
  u16* WtTV = (u16*)(ws + 16777216);           // 4 MiB  [Mt;Wvt][1024] bf16
  u16* Wqb = (u16*)(ws + 20971520);            // 2 MiB
  u16* Wkb = (u16*)(ws + 23068672);            // 2 MiB
  float* vvec = (float*)(ws + 25165824);       // 4 KiB
  float* cvec = (float*)(ws + 25169920);       // 32 KiB [8192]
  float* rowsum = (float*)(ws + 25202688);     // 32 KiB [8192]
  float* Mf32 = (float*)(ws + 25235456);       // 16 MiB (4 slices); T aliases
  u16* T = (u16*)(ws + 25235456);              // 16 MiB [8192][1024] bf16
  u16* Vt = (u16*)(ws + 42012672);             // 16 MiB [4][1024][2048] bf16
  u16* SP = (u16*)(ws + 58789888);             // 32 MiB [4][2048][2048] bf16

  // 1) prep: x-cast | W casts/transpose | vvec = Wk.bq
  prep<<<12288, 256, 0, stream>>>(x, Wq, Wk, Wv, bq, xb, Wqb, Wkb, WtTV,
                                  vvec);

  // 2) Mt = (Wq Wk^T)^T  split-K (4 x 256) f32 slices
  gemmM<<<dim3(8, 8, 4), 256, 0, stream>>>(Wkb, Wqb, Mf32, 1024, 256, 1024,
                                           256LL, 256LL, 1048576LL);

  // 3) merged: Mt sum-cast | cvec (+rowsum zero)
  mck<<<2048, 256, 0, stream>>>(Mf32, WtTV, xb, vvec, cvec, rowsum);

  // 4) fused T = x.Mt^T (bn<1024) | V-proj transposed; 8-phase, grid 256
  gemm8q<7><<<dim3(8, 32, 1), 512, 0, stream>>>(
      xb, WtTV, nullptr, nullptr, bv, T, Vt, 1024, 0, 0, 0, 0);

  // 5) P' = exp2(T.x^T*K2 + c2) bf16 + atomic rowsum; 8-phase, grid 256
  gemm8q<4><<<dim3(8, 8, 4), 512, 0, stream>>>(
      T, xb, cvec, rowsum, nullptr, SP, nullptr, 1024, 2048, 2097152LL,
      2097152LL, 4194304LL);

  // 6) out = (P'.V) / rowsum; grid 256
  gemm2t<5><<<dim3(4, 16, 4), 512, 0, stream>>>(
      SP, Vt, nullptr, rowsum, nullptr, out, nullptr, 2048, 1024, 4194304LL,
      2097152LL, 2097152LL);
}